// Round 1
// baseline (1087.356 us; speedup 1.0000x reference)
//
#include <hip/hip_runtime.h>
#include <math.h>

#define NN 6000
#define NSUB 4500
#define BB 8
#define DD 192
#define GD 40
#define KTOP 10
#define NLAY 3
#define ROWS (BB*NN)          // 48000
#define NEDGE (NN*(KTOP+1))   // 66000
#define WMAT (DD*DD)          // 36864

typedef unsigned short u16;
typedef unsigned int u32;
typedef __attribute__((ext_vector_type(8))) short bf16x8;
typedef __attribute__((ext_vector_type(4))) float f32x4;

__device__ __forceinline__ u16 f2b(float x){
  u32 u = __float_as_uint(x);
  u32 r = (u + 0x7fffu + ((u >> 16) & 1u)) >> 16;
  return (u16)r;
}
__device__ __forceinline__ float b2f(u16 h){
  u32 u = ((u32)h) << 16; return __uint_as_float(u);
}

// ---------------- graph-constructor prep: U,V tables ----------------
// U[i] = [0.5*nv1_i, 0.5*nv2_i], V[j] = [nv2_j, nv1_j]  (80 floats each)
__global__ void k_prep_uv(const float* __restrict__ emb1, const float* __restrict__ emb2,
                          const float* __restrict__ w1, const float* __restrict__ b1,
                          const float* __restrict__ w2, const float* __restrict__ b2,
                          float* __restrict__ U, float* __restrict__ V){
  int id = blockIdx.x*blockDim.x + threadIdx.x;
  if (id >= NN*GD) return;
  int i = id / GD, g = id % GD;
  float s1 = b1[g], s2 = b2[g];
  for (int k = 0; k < GD; k++){
    s1 += emb1[i*GD+k]*w1[k*GD+g];
    s2 += emb2[i*GD+k]*w2[k*GD+g];
  }
  float n1 = tanhf(3.0f*s1), n2 = tanhf(3.0f*s2);
  U[i*80+g]    = 0.5f*n1;  U[i*80+40+g] = 0.5f*n2;
  V[i*80+g]    = n2;       V[i*80+40+g] = n1;
}

// ---------------- pre-softplus score GEMM (fp32), one row-strip ----------------
// sbuf[r][j] = 0.5*(a+aT)[strip0+r][j] = sum_k U[strip0+r][k]*V[j][k]
__global__ void k_score(const float* __restrict__ U, const float* __restrict__ V,
                        float* __restrict__ sbuf, int strip0, int strip_rows){
  __shared__ float Ut[80*68];
  __shared__ float Vt[80*68];
  const int tid = threadIdx.x;
  const int i0 = blockIdx.y*64;   // row tile (strip-local)
  const int j0 = blockIdx.x*64;   // col tile (global)
  for (int t = tid; t < 64*80; t += 256){
    int k = t % 80, r = t / 80;
    int gi = strip0 + i0 + r; if (gi > NN-1) gi = NN-1;
    int gj = j0 + r;          if (gj > NN-1) gj = NN-1;
    Ut[k*68+r] = U[(size_t)gi*80 + k];
    Vt[k*68+r] = V[(size_t)gj*80 + k];
  }
  __syncthreads();
  const int ty = tid >> 4, tx = tid & 15;
  float acc[4][4];
  #pragma unroll
  for (int a = 0; a < 4; a++)
    #pragma unroll
    for (int b = 0; b < 4; b++) acc[a][b] = 0.f;
  for (int k = 0; k < 80; k++){
    float4 ua = *(const float4*)&Ut[k*68 + ty*4];
    float4 vb = *(const float4*)&Vt[k*68 + tx*4];
    float uar[4] = {ua.x, ua.y, ua.z, ua.w};
    float vbr[4] = {vb.x, vb.y, vb.z, vb.w};
    #pragma unroll
    for (int a = 0; a < 4; a++)
      #pragma unroll
      for (int b = 0; b < 4; b++) acc[a][b] += uar[a]*vbr[b];
  }
  #pragma unroll
  for (int a = 0; a < 4; a++){
    int ri = i0 + ty*4 + a;
    if (ri >= strip_rows) continue;
    #pragma unroll
    for (int b = 0; b < 4; b++){
      int cj = j0 + tx*4 + b;
      if (cj < NN) sbuf[(size_t)ri*NN + cj] = acc[a][b];
    }
  }
}

// ---------------- per-row top-k + degree/dis ----------------
__global__ __launch_bounds__(256) void k_topk(const float* __restrict__ sbuf,
                       int strip0, int strip_rows,
                       int* __restrict__ topcols, float* __restrict__ topvals,
                       float* __restrict__ dis){
  __shared__ float buf[NN];
  __shared__ float wmax[4]; __shared__ int widx[4];
  __shared__ int scol[KTOP]; __shared__ float sval[KTOP];
  int r = blockIdx.x; if (r >= strip_rows) return;
  int row = strip0 + r;
  const float* src = sbuf + (size_t)r*NN;
  for (int j = threadIdx.x; j < NN; j += blockDim.x) buf[j] = src[j];
  __syncthreads();
  const int lane = threadIdx.x & 63, w = threadIdx.x >> 6;
  for (int t = 0; t < KTOP; t++){
    float best = -__builtin_inff(); int bi = NN;
    for (int j = threadIdx.x; j < NN; j += blockDim.x){
      float v = buf[j];
      if (v > best || (v == best && j < bi)){ best = v; bi = j; }
    }
    for (int off = 32; off; off >>= 1){
      float ov = __shfl_down(best, off); int oi = __shfl_down(bi, off);
      if (ov > best || (ov == best && oi < bi)){ best = ov; bi = oi; }
    }
    if (lane == 0){ wmax[w] = best; widx[w] = bi; }
    __syncthreads();
    if (threadIdx.x == 0){
      for (int ww = 1; ww < 4; ww++){
        if (wmax[ww] > best || (wmax[ww] == best && widx[ww] < bi)){ best = wmax[ww]; bi = widx[ww]; }
      }
      scol[t] = bi; sval[t] = best; buf[bi] = -__builtin_inff();
    }
    __syncthreads();
  }
  if (threadIdx.x == 0){
    float d = 1.0f;
    for (int t = 0; t < KTOP; t++){
      float s = sval[t];
      float sp = (s > 20.f) ? s : log1pf(expf(s));
      float a = sp - 0.5f; if (a < 0.f) a = 0.f;
      topvals[row*KTOP+t] = a; topcols[row*KTOP+t] = scol[t];
      d += a;
    }
    dis[row] = rsqrtf(d);
  }
}

// ---------------- CSR (transpose graph) build ----------------
__global__ void k_count(const int* __restrict__ topcols, int* __restrict__ counts){
  int id = blockIdx.x*blockDim.x + threadIdx.x;
  if (id >= NEDGE) return;
  int n = id / (KTOP+1), e = id % (KTOP+1);
  int m = (e < KTOP) ? topcols[n*KTOP+e] : n;
  atomicAdd(&counts[m], 1);
}

__global__ __launch_bounds__(1024) void k_scan(const int* __restrict__ counts,
                                               int* __restrict__ rowptr, int* __restrict__ cursor){
  __shared__ int part[1024];
  int t = threadIdx.x;
  int local[6];
  int s = 0, base = t*6;
  for (int q = 0; q < 6; q++){
    int i = base + q; int c = (i < NN) ? counts[i] : 0;
    local[q] = s; s += c;
  }
  part[t] = s; __syncthreads();
  for (int off = 1; off < 1024; off <<= 1){
    int v = (t >= off) ? part[t-off] : 0;
    __syncthreads();
    part[t] += v;
    __syncthreads();
  }
  int excl = (t > 0) ? part[t-1] : 0;
  for (int q = 0; q < 6; q++){
    int i = base + q;
    if (i < NN){ int p = excl + local[q]; rowptr[i] = p; cursor[i] = p; }
  }
  if (t == 1023) rowptr[NN] = part[1023];
}

__global__ void k_fill(const int* __restrict__ topcols, const float* __restrict__ topvals,
                       const float* __restrict__ dis, int* __restrict__ cursor,
                       int* __restrict__ csr_src, float* __restrict__ csr_w){
  int id = blockIdx.x*blockDim.x + threadIdx.x;
  if (id >= NEDGE) return;
  int n = id / (KTOP+1), e = id % (KTOP+1);
  int m; float v;
  if (e < KTOP){ m = topcols[n*KTOP+e]; v = topvals[n*KTOP+e]; }
  else { m = n; v = 1.0f; }
  float w = v * dis[n] * dis[m];
  int pos = atomicAdd(&cursor[m], 1);
  csr_src[pos] = n; csr_w[pos] = w;
}

// ---------------- scatter (last occurrence wins, numpy semantics) ----------------
__global__ void k_winner(const int* __restrict__ idx, int* __restrict__ winner){
  int s = blockIdx.x*blockDim.x + threadIdx.x;
  if (s >= NSUB) return;
  atomicMax(&winner[idx[s]], s);
}

__global__ void k_h0(const float* __restrict__ subset, const float* __restrict__ uinit,
                     const int* __restrict__ winner, u16* __restrict__ h){
  int id = blockIdx.x*blockDim.x + threadIdx.x;
  if (id >= ROWS*DD) return;
  int c = id % DD; int bn = id / DD; int n = bn % NN; int b = bn / NN;
  int w = winner[n];
  float v = (w >= 0) ? subset[((size_t)b*NSUB + w)*DD + c] : uinit[c];
  h[id] = f2b(v);
}

// ---------------- weight transpose/convert: wbf[mat][n][k] = W[k][n] ----------------
__global__ void k_wprep(const float* __restrict__ mlp_w, const float* __restrict__ gate_w,
                        const float* __restrict__ diff_w, u16* __restrict__ wbf){
  int id = blockIdx.x*blockDim.x + threadIdx.x;
  if (id >= NLAY*5*WMAT) return;
  int mat = id / WMAT, rem = id % WMAT;
  int n = rem / DD, k = rem % DD;
  int layer = mat / 5, which = mat % 5;
  float v;
  if (which == 0)      v = mlp_w [((size_t)layer*DD   + k      )*DD + n];
  else if (which == 1) v = gate_w[((size_t)layer*2*DD + k      )*DD + n];
  else if (which == 2) v = gate_w[((size_t)layer*2*DD + DD + k )*DD + n];
  else if (which == 3) v = diff_w[((size_t)layer*2*DD + k      )*DD + n];
  else                 v = diff_w[((size_t)layer*2*DD + DD + k )*DD + n];
  wbf[id] = f2b(v);
}

// ---------------- SpMM: agg[b,m,:] = sum_in-edges w * h[b,src,:] ----------------
__global__ __launch_bounds__(192) void k_spmm(const u16* __restrict__ h, const int* __restrict__ rowptr,
                       const int* __restrict__ csr_src, const float* __restrict__ csr_w,
                       u16* __restrict__ agg){
  __shared__ int s_src[256]; __shared__ float s_w[256];
  int m = blockIdx.x; int c = threadIdx.x;
  int beg = rowptr[m], end = rowptr[m+1];
  float acc[BB];
  #pragma unroll
  for (int b = 0; b < BB; b++) acc[b] = 0.f;
  for (int base = beg; base < end; base += 256){
    int cnt = end - base; if (cnt > 256) cnt = 256;
    __syncthreads();
    for (int e = threadIdx.x; e < cnt; e += 192){ s_src[e] = csr_src[base+e]; s_w[e] = csr_w[base+e]; }
    __syncthreads();
    for (int e = 0; e < cnt; e++){
      int src = s_src[e]; float w = s_w[e];
      const u16* hp = h + (size_t)src*DD + c;
      #pragma unroll
      for (int b = 0; b < BB; b++) acc[b] += w * b2f(hp[(size_t)b*NN*DD]);
    }
  }
  #pragma unroll
  for (int b = 0; b < BB; b++) agg[((size_t)b*NN + m)*DD + c] = f2b(acc[b]);
}

// ---------------- fused layer: hn / gate / highway / diffusion (bf16 MFMA) ----------------
#define LP 200  // LDS row pitch in bf16 elems (192 + 8 pad -> conflict-free ds_read_b128)
__global__ __launch_bounds__(256) void k_layer(u16* __restrict__ h, const u16* __restrict__ agg,
                        const u16* __restrict__ wl, const float* __restrict__ mb,
                        const float* __restrict__ gb, const float* __restrict__ db){
  __shared__ u16 Ah[64*LP];
  __shared__ u16 Ax[64*LP];
  const int tid = threadIdx.x, lane = tid & 63, wave = tid >> 6;
  const int q = lane >> 4, ln = lane & 15;
  const int row0 = blockIdx.x*64;

  for (int i = tid; i < 64*24; i += 256){
    int r = i/24, c0 = i%24;
    ((uint4*)&Ah[r*LP])[c0] = ((const uint4*)h  )[(size_t)(row0+r)*24 + c0];
    ((uint4*)&Ax[r*LP])[c0] = ((const uint4*)agg)[(size_t)(row0+r)*24 + c0];
  }
  __syncthreads();

  f32x4 acc[12];
  const f32x4 zero = {0.f, 0.f, 0.f, 0.f};
  auto gemm = [&](const u16* Al, const u16* wp){
    for (int kk = 0; kk < 6; kk++){
      bf16x8 a = *(const bf16x8*)&Al[(wave*16 + ln)*LP + kk*32 + q*8];
      #pragma unroll
      for (int nt = 0; nt < 12; nt++){
        bf16x8 b = *(const bf16x8*)&wp[(nt*16 + ln)*DD + kk*32 + q*8];
        acc[nt] = __builtin_amdgcn_mfma_f32_16x16x32_bf16(a, b, acc[nt], 0, 0, 0);
      }
    }
  };
  const u16 *Wm = wl, *G1 = wl + WMAT, *G2 = wl + 2*WMAT, *D1 = wl + 3*WMAT, *D2 = wl + 4*WMAT;

  // GEMM1: hn = agg @ Wm + mb  -> Ax (wave-private rows, no barrier needed)
  #pragma unroll
  for (int i = 0; i < 12; i++) acc[i] = zero;
  gemm(Ax, Wm);
  #pragma unroll
  for (int nt = 0; nt < 12; nt++){
    int col = nt*16 + ln; float bias = mb[col];
    #pragma unroll
    for (int r = 0; r < 4; r++){
      int row = wave*16 + q*4 + r;
      Ax[row*LP + col] = f2b(acc[nt][r] + bias);
    }
  }
  // GEMM2: g = sigmoid(h@G1 + hn@G2 + gb); lo = g*hn + (1-g)*h -> Ax
  #pragma unroll
  for (int i = 0; i < 12; i++) acc[i] = zero;
  gemm(Ah, G1); gemm(Ax, G2);
  #pragma unroll
  for (int nt = 0; nt < 12; nt++){
    int col = nt*16 + ln; float bias = gb[col];
    #pragma unroll
    for (int r = 0; r < 4; r++){
      int row = wave*16 + q*4 + r; int off = row*LP + col;
      float g = 1.f/(1.f + expf(-(acc[nt][r] + bias)));
      float hv = b2f(Ah[off]), hnv = b2f(Ax[off]);
      Ax[off] = f2b(g*hnv + (1.f - g)*hv);
    }
  }
  // GEMM3: dg = sigmoid(h@D1 + lo@D2 + db); h' = dg*lo + (1-dg)*h -> Ah
  #pragma unroll
  for (int i = 0; i < 12; i++) acc[i] = zero;
  gemm(Ah, D1); gemm(Ax, D2);
  #pragma unroll
  for (int nt = 0; nt < 12; nt++){
    int col = nt*16 + ln; float bias = db[col];
    #pragma unroll
    for (int r = 0; r < 4; r++){
      int row = wave*16 + q*4 + r; int off = row*LP + col;
      float dg = 1.f/(1.f + expf(-(acc[nt][r] + bias)));
      float lov = b2f(Ax[off]), hv = b2f(Ah[off]);
      Ah[off] = f2b(dg*lov + (1.f - dg)*hv);
    }
  }
  __syncthreads();
  for (int i = tid; i < 64*24; i += 256){
    int r = i/24, c0 = i%24;
    ((uint4*)h)[(size_t)(row0+r)*24 + c0] = ((const uint4*)&Ah[r*LP])[c0];
  }
}

// ---------------- final confidence fusion (fp32 h0 path kept exact) ----------------
__global__ void k_final(const u16* __restrict__ h, const float* __restrict__ subset,
                        const int* __restrict__ winner, const float* __restrict__ ca_p,
                        float* __restrict__ out){
  int id = blockIdx.x*blockDim.x + threadIdx.x;
  if (id >= ROWS*DD) return;
  int c = id % DD; int bn = id / DD; int n = bn % NN; int b = bn / NN;
  float ca = ca_p[0];
  int w = winner[n];
  float hv = b2f(h[id]);
  float o;
  if (w >= 0){
    float h0 = subset[((size_t)b*NSUB + w)*DD + c];
    o = (1.0f - ca)*h0 + ca*hv;
  } else {
    o = hv;
  }
  out[id] = o;
}

extern "C" void kernel_launch(void* const* d_in, const int* in_sizes, int n_in,
                              void* d_out, int out_size, void* d_ws, size_t ws_size,
                              hipStream_t stream) {
  const float* subset = (const float*)d_in[0];
  const int*   idxs   = (const int*)  d_in[1];
  const float* emb1   = (const float*)d_in[2];
  const float* emb2   = (const float*)d_in[3];
  const float* l1w    = (const float*)d_in[4];
  const float* l1b    = (const float*)d_in[5];
  const float* l2w    = (const float*)d_in[6];
  const float* l2b    = (const float*)d_in[7];
  const float* uinit  = (const float*)d_in[8];
  const float* mlp_w  = (const float*)d_in[9];
  const float* mlp_b  = (const float*)d_in[10];
  const float* gate_w = (const float*)d_in[11];
  const float* gate_b = (const float*)d_in[12];
  const float* diff_w = (const float*)d_in[13];
  const float* diff_b = (const float*)d_in[14];
  const float* ca     = (const float*)d_in[15];
  float* out = (float*)d_out;

  char* base = (char*)d_ws; size_t off = 0;
  auto alloc = [&](size_t b)->void*{ void* p = base + off; off += b; off = (off + 255) & ~(size_t)255; return p; };
  float* U       = (float*)alloc((size_t)NN*80*4);
  float* V       = (float*)alloc((size_t)NN*80*4);
  u16*   h       = (u16*)  alloc((size_t)ROWS*DD*2);
  u16*   agg     = (u16*)  alloc((size_t)ROWS*DD*2);
  u16*   wbf     = (u16*)  alloc((size_t)NLAY*5*WMAT*2);
  int*   topcols = (int*)  alloc((size_t)NN*KTOP*4);
  float* topvals = (float*)alloc((size_t)NN*KTOP*4);
  float* dis     = (float*)alloc((size_t)NN*4);
  int*   winner  = (int*)  alloc((size_t)NN*4);
  int*   counts  = (int*)  alloc((size_t)NN*4);
  int*   rowptr  = (int*)  alloc((size_t)(NN+1)*4);
  int*   cursor  = (int*)  alloc((size_t)NN*4);
  int*   csr_src = (int*)  alloc((size_t)NEDGE*4);
  float* csr_w   = (float*)alloc((size_t)NEDGE*4);
  // strip score buffer takes the rest
  size_t avail = (ws_size > off) ? (ws_size - off) : 0;
  long maxrows = (long)(avail / ((size_t)NN*4));
  int R = (int)maxrows; if (R > 1500) R = 1500; if (R < 64) R = 64;
  float* sbuf = (float*)(base + off);

  // 1. graph constructor tables
  k_prep_uv<<<(NN*GD + 255)/256, 256, 0, stream>>>(emb1, emb2, l1w, l1b, l2w, l2b, U, V);

  // 2. score GEMM + top-k per strip (stream-serialized, buffer reused)
  for (int s0 = 0; s0 < NN; s0 += R){
    int rows = NN - s0; if (rows > R) rows = R;
    dim3 g((NN + 63)/64, (rows + 63)/64);
    k_score<<<g, 256, 0, stream>>>(U, V, sbuf, s0, rows);
    k_topk<<<rows, 256, 0, stream>>>(sbuf, s0, rows, topcols, topvals, dis);
  }

  // 3. CSR of transpose graph
  hipMemsetAsync(counts, 0, (size_t)NN*4, stream);
  k_count<<<(NEDGE + 255)/256, 256, 0, stream>>>(topcols, counts);
  k_scan<<<1, 1024, 0, stream>>>(counts, rowptr, cursor);
  k_fill<<<(NEDGE + 255)/256, 256, 0, stream>>>(topcols, topvals, dis, cursor, csr_src, csr_w);

  // 4. scatter init
  hipMemsetAsync(winner, 0xFF, (size_t)NN*4, stream);
  k_winner<<<(NSUB + 255)/256, 256, 0, stream>>>(idxs, winner);
  k_h0<<<(ROWS*DD + 255)/256, 256, 0, stream>>>(subset, uinit, winner, h);

  // 5. weights -> bf16 transposed
  k_wprep<<<(NLAY*5*WMAT + 255)/256, 256, 0, stream>>>(mlp_w, gate_w, diff_w, wbf);

  // 6. layers
  for (int l = 0; l < NLAY; l++){
    k_spmm<<<NN, 192, 0, stream>>>(h, rowptr, csr_src, csr_w, agg);
    k_layer<<<ROWS/64, 256, 0, stream>>>(h, agg, wbf + (size_t)l*5*WMAT,
                                         mlp_b + l*DD, gate_b + l*DD, diff_b + l*DD);
  }

  // 7. confidence fusion
  k_final<<<(ROWS*DD + 255)/256, 256, 0, stream>>>(h, subset, winner, ca, out);
}

// Round 2
// 804.932 us; speedup vs baseline: 1.3509x; 1.3509x over previous
//
#include <hip/hip_runtime.h>
#include <math.h>

#define NN 6000
#define NSUB 4500
#define BB 8
#define DD 192
#define GD 40
#define KTOP 10
#define NLAY 3
#define ROWS (BB*NN)          // 48000
#define NEDGE (NN*(KTOP+1))   // 66000
#define WMAT (DD*DD)          // 36864

typedef unsigned short u16;
typedef unsigned int u32;
typedef __attribute__((ext_vector_type(8))) short bf16x8;
typedef __attribute__((ext_vector_type(4))) float f32x4;

__device__ __forceinline__ u16 f2b(float x){
  u32 u = __float_as_uint(x);
  u32 r = (u + 0x7fffu + ((u >> 16) & 1u)) >> 16;
  return (u16)r;
}
__device__ __forceinline__ float b2f(u16 h){
  u32 u = ((u32)h) << 16; return __uint_as_float(u);
}

// ---------------- graph-constructor prep: U,V tables ----------------
// U[i] = [0.5*nv1_i, 0.5*nv2_i], V[j] = [nv2_j, nv1_j]  (80 floats each)
__global__ void k_prep_uv(const float* __restrict__ emb1, const float* __restrict__ emb2,
                          const float* __restrict__ w1, const float* __restrict__ b1,
                          const float* __restrict__ w2, const float* __restrict__ b2,
                          float* __restrict__ U, float* __restrict__ V){
  int id = blockIdx.x*blockDim.x + threadIdx.x;
  if (id >= NN*GD) return;
  int i = id / GD, g = id % GD;
  float s1 = b1[g], s2 = b2[g];
  for (int k = 0; k < GD; k++){
    s1 += emb1[i*GD+k]*w1[k*GD+g];
    s2 += emb2[i*GD+k]*w2[k*GD+g];
  }
  float n1 = tanhf(3.0f*s1), n2 = tanhf(3.0f*s2);
  U[i*80+g]    = 0.5f*n1;  U[i*80+40+g] = 0.5f*n2;
  V[i*80+g]    = n2;       V[i*80+40+g] = n1;
}

// ---------------- pre-softplus score GEMM (fp32), one row-strip ----------------
// sbuf[r][j] = 0.5*(a+aT)[strip0+r][j] = sum_k U[strip0+r][k]*V[j][k]
__global__ void k_score(const float* __restrict__ U, const float* __restrict__ V,
                        float* __restrict__ sbuf, int strip0, int strip_rows){
  __shared__ float Ut[80*68];
  __shared__ float Vt[80*68];
  const int tid = threadIdx.x;
  const int i0 = blockIdx.y*64;   // row tile (strip-local)
  const int j0 = blockIdx.x*64;   // col tile (global)
  for (int t = tid; t < 64*80; t += 256){
    int k = t % 80, r = t / 80;
    int gi = strip0 + i0 + r; if (gi > NN-1) gi = NN-1;
    int gj = j0 + r;          if (gj > NN-1) gj = NN-1;
    Ut[k*68+r] = U[(size_t)gi*80 + k];
    Vt[k*68+r] = V[(size_t)gj*80 + k];
  }
  __syncthreads();
  const int ty = tid >> 4, tx = tid & 15;
  float acc[4][4];
  #pragma unroll
  for (int a = 0; a < 4; a++)
    #pragma unroll
    for (int b = 0; b < 4; b++) acc[a][b] = 0.f;
  for (int k = 0; k < 80; k++){
    float4 ua = *(const float4*)&Ut[k*68 + ty*4];
    float4 vb = *(const float4*)&Vt[k*68 + tx*4];
    float uar[4] = {ua.x, ua.y, ua.z, ua.w};
    float vbr[4] = {vb.x, vb.y, vb.z, vb.w};
    #pragma unroll
    for (int a = 0; a < 4; a++)
      #pragma unroll
      for (int b = 0; b < 4; b++) acc[a][b] += uar[a]*vbr[b];
  }
  #pragma unroll
  for (int a = 0; a < 4; a++){
    int ri = i0 + ty*4 + a;
    if (ri >= strip_rows) continue;
    #pragma unroll
    for (int b = 0; b < 4; b++){
      int cj = j0 + tx*4 + b;
      if (cj < NN) sbuf[(size_t)ri*NN + cj] = acc[a][b];
    }
  }
}

// ---------------- per-row top-k + degree/dis ----------------
__global__ __launch_bounds__(256) void k_topk(const float* __restrict__ sbuf,
                       int strip0, int strip_rows,
                       int* __restrict__ topcols, float* __restrict__ topvals,
                       float* __restrict__ dis){
  __shared__ float buf[NN];
  __shared__ float wmax[4]; __shared__ int widx[4];
  __shared__ int scol[KTOP]; __shared__ float sval[KTOP];
  int r = blockIdx.x; if (r >= strip_rows) return;
  int row = strip0 + r;
  const float* src = sbuf + (size_t)r*NN;
  for (int j = threadIdx.x; j < NN; j += blockDim.x) buf[j] = src[j];
  __syncthreads();
  const int lane = threadIdx.x & 63, w = threadIdx.x >> 6;
  for (int t = 0; t < KTOP; t++){
    float best = -__builtin_inff(); int bi = NN;
    for (int j = threadIdx.x; j < NN; j += blockDim.x){
      float v = buf[j];
      if (v > best || (v == best && j < bi)){ best = v; bi = j; }
    }
    for (int off = 32; off; off >>= 1){
      float ov = __shfl_down(best, off); int oi = __shfl_down(bi, off);
      if (ov > best || (ov == best && oi < bi)){ best = ov; bi = oi; }
    }
    if (lane == 0){ wmax[w] = best; widx[w] = bi; }
    __syncthreads();
    if (threadIdx.x == 0){
      for (int ww = 1; ww < 4; ww++){
        if (wmax[ww] > best || (wmax[ww] == best && widx[ww] < bi)){ best = wmax[ww]; bi = widx[ww]; }
      }
      scol[t] = bi; sval[t] = best; buf[bi] = -__builtin_inff();
    }
    __syncthreads();
  }
  if (threadIdx.x == 0){
    float d = 1.0f;
    for (int t = 0; t < KTOP; t++){
      float s = sval[t];
      float sp = (s > 20.f) ? s : log1pf(expf(s));
      float a = sp - 0.5f; if (a < 0.f) a = 0.f;
      topvals[row*KTOP+t] = a; topcols[row*KTOP+t] = scol[t];
      d += a;
    }
    dis[row] = rsqrtf(d);
  }
}

// ---------------- CSR (transpose graph) build ----------------
__global__ void k_count(const int* __restrict__ topcols, int* __restrict__ counts){
  int id = blockIdx.x*blockDim.x + threadIdx.x;
  if (id >= NEDGE) return;
  int n = id / (KTOP+1), e = id % (KTOP+1);
  int m = (e < KTOP) ? topcols[n*KTOP+e] : n;
  atomicAdd(&counts[m], 1);
}

__global__ __launch_bounds__(1024) void k_scan(const int* __restrict__ counts,
                                               int* __restrict__ rowptr, int* __restrict__ cursor){
  __shared__ int part[1024];
  int t = threadIdx.x;
  int local[6];
  int s = 0, base = t*6;
  for (int q = 0; q < 6; q++){
    int i = base + q; int c = (i < NN) ? counts[i] : 0;
    local[q] = s; s += c;
  }
  part[t] = s; __syncthreads();
  for (int off = 1; off < 1024; off <<= 1){
    int v = (t >= off) ? part[t-off] : 0;
    __syncthreads();
    part[t] += v;
    __syncthreads();
  }
  int excl = (t > 0) ? part[t-1] : 0;
  for (int q = 0; q < 6; q++){
    int i = base + q;
    if (i < NN){ int p = excl + local[q]; rowptr[i] = p; cursor[i] = p; }
  }
  if (t == 1023) rowptr[NN] = part[1023];
}

__global__ void k_fill(const int* __restrict__ topcols, const float* __restrict__ topvals,
                       const float* __restrict__ dis, int* __restrict__ cursor,
                       int* __restrict__ csr_src, float* __restrict__ csr_w){
  int id = blockIdx.x*blockDim.x + threadIdx.x;
  if (id >= NEDGE) return;
  int n = id / (KTOP+1), e = id % (KTOP+1);
  int m; float v;
  if (e < KTOP){ m = topcols[n*KTOP+e]; v = topvals[n*KTOP+e]; }
  else { m = n; v = 1.0f; }
  float w = v * dis[n] * dis[m];
  int pos = atomicAdd(&cursor[m], 1);
  csr_src[pos] = n; csr_w[pos] = w;
}

// ---------------- scatter (last occurrence wins, numpy semantics) ----------------
__global__ void k_winner(const int* __restrict__ idx, int* __restrict__ winner){
  int s = blockIdx.x*blockDim.x + threadIdx.x;
  if (s >= NSUB) return;
  atomicMax(&winner[idx[s]], s);
}

__global__ void k_h0(const float* __restrict__ subset, const float* __restrict__ uinit,
                     const int* __restrict__ winner, u16* __restrict__ h){
  int id = blockIdx.x*blockDim.x + threadIdx.x;
  if (id >= ROWS*DD) return;
  int c = id % DD; int bn = id / DD; int n = bn % NN; int b = bn / NN;
  int w = winner[n];
  float v = (w >= 0) ? subset[((size_t)b*NSUB + w)*DD + c] : uinit[c];
  h[id] = f2b(v);
}

// ---------------- weight transpose/convert: wbf[mat][n][k] = W[k][n] ----------------
__global__ void k_wprep(const float* __restrict__ mlp_w, const float* __restrict__ gate_w,
                        const float* __restrict__ diff_w, u16* __restrict__ wbf){
  int id = blockIdx.x*blockDim.x + threadIdx.x;
  if (id >= NLAY*5*WMAT) return;
  int mat = id / WMAT, rem = id % WMAT;
  int n = rem / DD, k = rem % DD;
  int layer = mat / 5, which = mat % 5;
  float v;
  if (which == 0)      v = mlp_w [((size_t)layer*DD   + k      )*DD + n];
  else if (which == 1) v = gate_w[((size_t)layer*2*DD + k      )*DD + n];
  else if (which == 2) v = gate_w[((size_t)layer*2*DD + DD + k )*DD + n];
  else if (which == 3) v = diff_w[((size_t)layer*2*DD + k      )*DD + n];
  else                 v = diff_w[((size_t)layer*2*DD + DD + k )*DD + n];
  wbf[id] = f2b(v);
}

// ---------------- SpMM: agg[b,m,:] = sum_in-edges w * h[b,src,:] ----------------
__global__ __launch_bounds__(192) void k_spmm(const u16* __restrict__ h, const int* __restrict__ rowptr,
                       const int* __restrict__ csr_src, const float* __restrict__ csr_w,
                       u16* __restrict__ agg){
  __shared__ int s_src[256]; __shared__ float s_w[256];
  int m = blockIdx.x; int c = threadIdx.x;
  int beg = rowptr[m], end = rowptr[m+1];
  float acc[BB];
  #pragma unroll
  for (int b = 0; b < BB; b++) acc[b] = 0.f;
  for (int base = beg; base < end; base += 256){
    int cnt = end - base; if (cnt > 256) cnt = 256;
    __syncthreads();
    for (int e = threadIdx.x; e < cnt; e += 192){ s_src[e] = csr_src[base+e]; s_w[e] = csr_w[base+e]; }
    __syncthreads();
    for (int e = 0; e < cnt; e++){
      int src = s_src[e]; float w = s_w[e];
      const u16* hp = h + (size_t)src*DD + c;
      #pragma unroll
      for (int b = 0; b < BB; b++) acc[b] += w * b2f(hp[(size_t)b*NN*DD]);
    }
  }
  #pragma unroll
  for (int b = 0; b < BB; b++) agg[((size_t)b*NN + m)*DD + c] = f2b(acc[b]);
}

// ---------------- fused layer: hn / gate / highway / diffusion (bf16 MFMA) ----------------
// Wave w owns col-tiles {3w,3w+1,3w+2}; B fragments register-resident per stage.
#define LP 200  // LDS row pitch in bf16 elems (192 + 8 pad)
__global__ __launch_bounds__(256, 2) void k_layer(u16* __restrict__ h, const u16* __restrict__ agg,
                        const u16* __restrict__ wl, const float* __restrict__ mb,
                        const float* __restrict__ gb, const float* __restrict__ db){
  __shared__ u16 Ah[64*LP];
  __shared__ u16 Ax[64*LP];
  const int tid = threadIdx.x, lane = tid & 63, wave = tid >> 6;
  const int q = lane >> 4, ln = lane & 15;
  const int row0 = blockIdx.x*64;

  for (int i = tid; i < 64*24; i += 256){
    int r = i/24, c0 = i%24;
    ((uint4*)&Ah[r*LP])[c0] = ((const uint4*)h  )[(size_t)(row0+r)*24 + c0];
    ((uint4*)&Ax[r*LP])[c0] = ((const uint4*)agg)[(size_t)(row0+r)*24 + c0];
  }
  __syncthreads();

  const u16 *Wm = wl, *G1 = wl + WMAT, *G2 = wl + 2*WMAT, *D1 = wl + 3*WMAT, *D2 = wl + 4*WMAT;

  f32x4 acc[4][3];
  bf16x8 Bf[6][3];

  auto loadB = [&](const u16* wp){
    #pragma unroll
    for (int kk = 0; kk < 6; kk++)
      #pragma unroll
      for (int ntl = 0; ntl < 3; ntl++){
        int nt = wave*3 + ntl;
        Bf[kk][ntl] = *(const bf16x8*)&wp[(size_t)(nt*16 + ln)*DD + kk*32 + q*8];
      }
  };
  auto gemm = [&](const u16* Al){
    #pragma unroll
    for (int kk = 0; kk < 6; kk++){
      bf16x8 a[4];
      #pragma unroll
      for (int rt = 0; rt < 4; rt++)
        a[rt] = *(const bf16x8*)&Al[(rt*16 + ln)*LP + kk*32 + q*8];
      #pragma unroll
      for (int rt = 0; rt < 4; rt++)
        #pragma unroll
        for (int ntl = 0; ntl < 3; ntl++)
          acc[rt][ntl] = __builtin_amdgcn_mfma_f32_16x16x32_bf16(a[rt], Bf[kk][ntl], acc[rt][ntl], 0, 0, 0);
    }
  };
  auto zacc = [&](){
    #pragma unroll
    for (int rt = 0; rt < 4; rt++)
      #pragma unroll
      for (int ntl = 0; ntl < 3; ntl++)
        acc[rt][ntl] = (f32x4){0.f, 0.f, 0.f, 0.f};
  };

  // ---- stage 1: hn = agg @ Wm + mb  -> Ax
  zacc(); loadB(Wm); gemm(Ax);
  __syncthreads();                       // everyone done reading Ax(agg)
  #pragma unroll
  for (int ntl = 0; ntl < 3; ntl++){
    int col = (wave*3 + ntl)*16 + ln; float bias = mb[col];
    #pragma unroll
    for (int rt = 0; rt < 4; rt++)
      #pragma unroll
      for (int r = 0; r < 4; r++)
        Ax[(rt*16 + q*4 + r)*LP + col] = f2b(acc[rt][ntl][r] + bias);
  }
  __syncthreads();                       // hn visible to all

  // ---- stage 2: g = sigmoid(h@G1 + hn@G2 + gb); lo = g*hn + (1-g)*h -> Ax
  zacc(); loadB(G1); gemm(Ah); loadB(G2); gemm(Ax);
  __syncthreads();                       // everyone done reading Ax(hn)
  #pragma unroll
  for (int ntl = 0; ntl < 3; ntl++){
    int col = (wave*3 + ntl)*16 + ln; float bias = gb[col];
    #pragma unroll
    for (int rt = 0; rt < 4; rt++)
      #pragma unroll
      for (int r = 0; r < 4; r++){
        int off = (rt*16 + q*4 + r)*LP + col;
        float g = 1.f/(1.f + expf(-(acc[rt][ntl][r] + bias)));
        float hv = b2f(Ah[off]), hnv = b2f(Ax[off]);
        Ax[off] = f2b(g*hnv + (1.f - g)*hv);
      }
  }
  __syncthreads();                       // lo visible to all

  // ---- stage 3: dg = sigmoid(h@D1 + lo@D2 + db); h' = dg*lo + (1-dg)*h -> global
  zacc(); loadB(D1); gemm(Ah); loadB(D2); gemm(Ax);
  #pragma unroll
  for (int ntl = 0; ntl < 3; ntl++){
    int col = (wave*3 + ntl)*16 + ln; float bias = db[col];
    #pragma unroll
    for (int rt = 0; rt < 4; rt++)
      #pragma unroll
      for (int r = 0; r < 4; r++){
        int row = rt*16 + q*4 + r; int off = row*LP + col;
        float dg = 1.f/(1.f + expf(-(acc[rt][ntl][r] + bias)));
        float lov = b2f(Ax[off]), hv = b2f(Ah[off]);
        h[(size_t)(row0 + row)*DD + col] = f2b(dg*lov + (1.f - dg)*hv);
      }
  }
}

// ---------------- final confidence fusion (fp32 h0 path kept exact) ----------------
__global__ void k_final(const u16* __restrict__ h, const float* __restrict__ subset,
                        const int* __restrict__ winner, const float* __restrict__ ca_p,
                        float* __restrict__ out){
  int id = blockIdx.x*blockDim.x + threadIdx.x;
  if (id >= ROWS*DD) return;
  int c = id % DD; int bn = id / DD; int n = bn % NN; int b = bn / NN;
  float ca = ca_p[0];
  int w = winner[n];
  float hv = b2f(h[id]);
  float o;
  if (w >= 0){
    float h0 = subset[((size_t)b*NSUB + w)*DD + c];
    o = (1.0f - ca)*h0 + ca*hv;
  } else {
    o = hv;
  }
  out[id] = o;
}

extern "C" void kernel_launch(void* const* d_in, const int* in_sizes, int n_in,
                              void* d_out, int out_size, void* d_ws, size_t ws_size,
                              hipStream_t stream) {
  const float* subset = (const float*)d_in[0];
  const int*   idxs   = (const int*)  d_in[1];
  const float* emb1   = (const float*)d_in[2];
  const float* emb2   = (const float*)d_in[3];
  const float* l1w    = (const float*)d_in[4];
  const float* l1b    = (const float*)d_in[5];
  const float* l2w    = (const float*)d_in[6];
  const float* l2b    = (const float*)d_in[7];
  const float* uinit  = (const float*)d_in[8];
  const float* mlp_w  = (const float*)d_in[9];
  const float* mlp_b  = (const float*)d_in[10];
  const float* gate_w = (const float*)d_in[11];
  const float* gate_b = (const float*)d_in[12];
  const float* diff_w = (const float*)d_in[13];
  const float* diff_b = (const float*)d_in[14];
  const float* ca     = (const float*)d_in[15];
  float* out = (float*)d_out;

  char* base = (char*)d_ws; size_t off = 0;
  auto alloc = [&](size_t b)->void*{ void* p = base + off; off += b; off = (off + 255) & ~(size_t)255; return p; };
  float* U       = (float*)alloc((size_t)NN*80*4);
  float* V       = (float*)alloc((size_t)NN*80*4);
  u16*   h       = (u16*)  alloc((size_t)ROWS*DD*2);
  u16*   agg     = (u16*)  alloc((size_t)ROWS*DD*2);
  u16*   wbf     = (u16*)  alloc((size_t)NLAY*5*WMAT*2);
  int*   topcols = (int*)  alloc((size_t)NN*KTOP*4);
  float* topvals = (float*)alloc((size_t)NN*KTOP*4);
  float* dis     = (float*)alloc((size_t)NN*4);
  int*   winner  = (int*)  alloc((size_t)NN*4);
  int*   counts  = (int*)  alloc((size_t)NN*4);
  int*   rowptr  = (int*)  alloc((size_t)(NN+1)*4);
  int*   cursor  = (int*)  alloc((size_t)NN*4);
  int*   csr_src = (int*)  alloc((size_t)NEDGE*4);
  float* csr_w   = (float*)alloc((size_t)NEDGE*4);
  // strip score buffer takes the rest
  size_t avail = (ws_size > off) ? (ws_size - off) : 0;
  long maxrows = (long)(avail / ((size_t)NN*4));
  int R = (int)maxrows; if (R > 1500) R = 1500; if (R < 64) R = 64;
  float* sbuf = (float*)(base + off);

  // 1. graph constructor tables
  k_prep_uv<<<(NN*GD + 255)/256, 256, 0, stream>>>(emb1, emb2, l1w, l1b, l2w, l2b, U, V);

  // 2. score GEMM + top-k per strip (stream-serialized, buffer reused)
  for (int s0 = 0; s0 < NN; s0 += R){
    int rows = NN - s0; if (rows > R) rows = R;
    dim3 g((NN + 63)/64, (rows + 63)/64);
    k_score<<<g, 256, 0, stream>>>(U, V, sbuf, s0, rows);
    k_topk<<<rows, 256, 0, stream>>>(sbuf, s0, rows, topcols, topvals, dis);
  }

  // 3. CSR of transpose graph
  hipMemsetAsync(counts, 0, (size_t)NN*4, stream);
  k_count<<<(NEDGE + 255)/256, 256, 0, stream>>>(topcols, counts);
  k_scan<<<1, 1024, 0, stream>>>(counts, rowptr, cursor);
  k_fill<<<(NEDGE + 255)/256, 256, 0, stream>>>(topcols, topvals, dis, cursor, csr_src, csr_w);

  // 4. scatter init
  hipMemsetAsync(winner, 0xFF, (size_t)NN*4, stream);
  k_winner<<<(NSUB + 255)/256, 256, 0, stream>>>(idxs, winner);
  k_h0<<<(ROWS*DD + 255)/256, 256, 0, stream>>>(subset, uinit, winner, h);

  // 5. weights -> bf16 transposed
  k_wprep<<<(NLAY*5*WMAT + 255)/256, 256, 0, stream>>>(mlp_w, gate_w, diff_w, wbf);

  // 6. layers
  for (int l = 0; l < NLAY; l++){
    k_spmm<<<NN, 192, 0, stream>>>(h, rowptr, csr_src, csr_w, agg);
    k_layer<<<ROWS/64, 256, 0, stream>>>(h, agg, wbf + (size_t)l*5*WMAT,
                                         mlp_b + l*DD, gate_b + l*DD, diff_b + l*DD);
  }

  // 7. confidence fusion
  k_final<<<(ROWS*DD + 255)/256, 256, 0, stream>>>(h, subset, winner, ca, out);
}

// Round 3
// 649.620 us; speedup vs baseline: 1.6738x; 1.2391x over previous
//
#include <hip/hip_runtime.h>
#include <math.h>

#define NN 6000
#define NSUB 4500
#define BB 8
#define DD 192
#define GD 40
#define KTOP 10
#define NLAY 3
#define ROWS (BB*NN)          // 48000
#define NEDGE (NN*(KTOP+1))   // 66000
#define WMAT (DD*DD)          // 36864
#define NSTRIP 8
#define SCOLS 750             // cols per strip (8*750 = 6000)
#define NTILE 12              // ceil(750/64)
#define RCAP 6016             // padded row capacity for partials

typedef unsigned short u16;
typedef unsigned int u32;
typedef __attribute__((ext_vector_type(8))) short bf16x8;
typedef __attribute__((ext_vector_type(4))) float f32x4;

__device__ __forceinline__ u16 f2b(float x){
  u32 u = __float_as_uint(x);
  u32 r = (u + 0x7fffu + ((u >> 16) & 1u)) >> 16;
  return (u16)r;
}
__device__ __forceinline__ float b2f(u16 h){
  u32 u = ((u32)h) << 16; return __uint_as_float(u);
}
// order-preserving monotone float->uint key
__device__ __forceinline__ u32 fkey(float f){
  u32 b = __float_as_uint(f);
  return (b & 0x80000000u) ? ~b : (b | 0x80000000u);
}

// ---------------- graph-constructor prep: U,V tables ----------------
__global__ void k_prep_uv(const float* __restrict__ emb1, const float* __restrict__ emb2,
                          const float* __restrict__ w1, const float* __restrict__ b1,
                          const float* __restrict__ w2, const float* __restrict__ b2,
                          float* __restrict__ U, float* __restrict__ V){
  int id = blockIdx.x*blockDim.x + threadIdx.x;
  if (id >= NN*GD) return;
  int i = id / GD, g = id % GD;
  float s1 = b1[g], s2 = b2[g];
  for (int k = 0; k < GD; k++){
    s1 += emb1[i*GD+k]*w1[k*GD+g];
    s2 += emb2[i*GD+k]*w2[k*GD+g];
  }
  float n1 = tanhf(3.0f*s1), n2 = tanhf(3.0f*s2);
  U[i*80+g]    = 0.5f*n1;  U[i*80+40+g] = 0.5f*n2;
  V[i*80+g]    = n2;       V[i*80+40+g] = n1;
}

// ---------------- fused score + streaming top-k (per row-block x col-strip) ----------------
// Ut/Vt: [k 0..79][pitch 68] transposed tiles. Sc: [col 0..63][pitch 68 over rows].
__global__ __launch_bounds__(256, 2) void k_scoretopk(const float* __restrict__ U, const float* __restrict__ V,
                          float* __restrict__ ptv, int* __restrict__ ptc){
  __shared__ float Ut[80*68];
  __shared__ float Vt[80*68];
  __shared__ float Sc[64*68];
  __shared__ u32 rowthr[64];
  const int tid = threadIdx.x;
  const int r0 = blockIdx.x*64;
  const int y  = blockIdx.y;
  const int cstart = y*SCOLS, cend = cstart + SCOLS;
  const float NINF = -__builtin_inff();

  // stage Ut[k][r] = U[r0+r][k] (float4 global, scalar LDS writes conflict-free: lanes vary r)
  for (int f4 = tid; f4 < 64*20; f4 += 256){
    int r = f4 & 63, c4 = f4 >> 6;
    int gr = r0 + r; if (gr > NN-1) gr = NN-1;
    float4 u = *(const float4*)&U[(size_t)gr*80 + c4*4];
    Ut[(c4*4+0)*68 + r] = u.x; Ut[(c4*4+1)*68 + r] = u.y;
    Ut[(c4*4+2)*68 + r] = u.z; Ut[(c4*4+3)*68 + r] = u.w;
  }
  if (tid < 64) rowthr[tid] = 0u;

  float tv[10]; int ti[10];
  #pragma unroll
  for (int s = 0; s < 10; s++){ tv[s] = NINF; ti[s] = NN; }

  const int tx = tid & 15, ty = tid >> 4;    // compute mapping: rows 4ty..+3, cols 4tx..+3
  const int rho = tid & 63, cg = tid >> 6;   // scan mapping: row rho, cols 16cg..+15

  for (int t = 0; t < NTILE; t++){
    int cb = cstart + t*64;
    __syncthreads();   // Vt safe to overwrite (prev compute done), Sc safe (prev scan done)
    for (int f4 = tid; f4 < 64*20; f4 += 256){
      int c = f4 & 63, c4 = f4 >> 6;
      int gc = cb + c; if (gc > NN-1) gc = NN-1;
      float4 v = *(const float4*)&V[(size_t)gc*80 + c4*4];
      Vt[(c4*4+0)*68 + c] = v.x; Vt[(c4*4+1)*68 + c] = v.y;
      Vt[(c4*4+2)*68 + c] = v.z; Vt[(c4*4+3)*68 + c] = v.w;
    }
    __syncthreads();
    // compute 64x64 scores
    float acc[4][4];
    #pragma unroll
    for (int a = 0; a < 4; a++)
      #pragma unroll
      for (int b = 0; b < 4; b++) acc[a][b] = 0.f;
    for (int k = 0; k < 80; k++){
      float4 ua = *(const float4*)&Ut[k*68 + ty*4];
      float4 vb = *(const float4*)&Vt[k*68 + tx*4];
      float uar[4] = {ua.x, ua.y, ua.z, ua.w};
      float vbr[4] = {vb.x, vb.y, vb.z, vb.w};
      #pragma unroll
      for (int a = 0; a < 4; a++)
        #pragma unroll
        for (int b = 0; b < 4; b++) acc[a][b] += uar[a]*vbr[b];
    }
    #pragma unroll
    for (int dc = 0; dc < 4; dc++){
      float4 w; w.x = acc[0][dc]; w.y = acc[1][dc]; w.z = acc[2][dc]; w.w = acc[3][dc];
      *(float4*)&Sc[(tx*4+dc)*68 + ty*4] = w;
    }
    __syncthreads();
    // streaming scan with shared-threshold pruning
    u32 Treg = rowthr[rho];
    for (int i = 0; i < 16; i++){
      int c = cg*16 + i; int j = cb + c;
      if (j >= cend) break;
      float v = Sc[c*68 + rho];
      u32 uk = fkey(v);
      if (uk > Treg && v > tv[9]){
        bool b[9];
        #pragma unroll
        for (int k = 0; k < 9; k++) b[k] = v > tv[k];
        #pragma unroll
        for (int k = 9; k >= 1; k--){
          bool bh = b[k-1];
          bool bk = (k == 9) ? true : b[k];
          tv[k] = bh ? tv[k-1] : (bk ? v : tv[k]);
          ti[k] = bh ? ti[k-1] : (bk ? j : ti[k]);
        }
        if (b[0]){ tv[0] = v; ti[0] = j; }
        u32 k9 = fkey(tv[9]);
        if (k9 > Treg) Treg = k9;
        atomicMax(&rowthr[rho], k9);
      }
    }
  }
  // ---- per-strip merge of the 4 cg lists (overlay on Ut) ----
  __syncthreads();
  float* candv = Ut;                       // 64*41 floats
  int*   candi = (int*)(Ut + 64*41);       // 64*41 ints
  #pragma unroll
  for (int s = 0; s < 10; s++){
    candv[rho*41 + cg*10 + s] = tv[s];
    candi[rho*41 + cg*10 + s] = ti[s];
  }
  __syncthreads();
  if (tid < 64 && r0 + tid < NN){
    int row = tid;
    u32 P = 0;  // 4 x 8-bit pointers
    for (int s = 0; s < 10; s++){
      float bv = NINF; int bi = NN; int by = 0;
      #pragma unroll
      for (int g = 0; g < 4; g++){
        u32 pg = (P >> (8*g)) & 255u;
        u32 pc = pg < 9u ? pg : 9u;
        float v = candv[row*41 + g*10 + pc];
        int  jj = candi[row*41 + g*10 + pc];
        if (pg >= 10u){ v = NINF; jj = NN; }
        if (v > bv || (v == bv && jj < bi)){ bv = v; bi = jj; by = g; }
      }
      P += (1u << (8*by));
      size_t o = ((size_t)y*RCAP + r0 + row)*10 + s;
      ptv[o] = bv; ptc[o] = bi;
    }
  }
}

// ---------------- merge 8 strip partials -> final topk + softplus + dis ----------------
__global__ void k_mergetopk(const float* __restrict__ ptv, const int* __restrict__ ptc,
                            int* __restrict__ topcols, float* __restrict__ topvals,
                            float* __restrict__ dis){
  int r = blockIdx.x*blockDim.x + threadIdx.x;
  if (r >= NN) return;
  const float NINF = -__builtin_inff();
  unsigned long long P = 0;  // 8 x 8-bit pointers
  float d = 1.0f;
  for (int s = 0; s < 10; s++){
    float bv = NINF; int bi = NN; int by = 0;
    #pragma unroll
    for (int g = 0; g < 8; g++){
      u32 pg = (u32)((P >> (8*g)) & 255u);
      u32 pc = pg < 9u ? pg : 9u;
      size_t o = ((size_t)g*RCAP + r)*10 + pc;
      float v = ptv[o]; int jj = ptc[o];
      if (pg >= 10u){ v = NINF; jj = NN; }
      if (v > bv || (v == bv && jj < bi)){ bv = v; bi = jj; by = g; }
    }
    P += (1ull << (8*by));
    float sp = (bv > 20.f) ? bv : log1pf(expf(bv));
    float a = sp - 0.5f; if (a < 0.f) a = 0.f;
    topvals[r*KTOP + s] = a; topcols[r*KTOP + s] = bi;
    d += a;
  }
  dis[r] = rsqrtf(d);
}

// ---------------- CSR (transpose graph) build ----------------
__global__ void k_count(const int* __restrict__ topcols, int* __restrict__ counts){
  int id = blockIdx.x*blockDim.x + threadIdx.x;
  if (id >= NEDGE) return;
  int n = id / (KTOP+1), e = id % (KTOP+1);
  int m = (e < KTOP) ? topcols[n*KTOP+e] : n;
  atomicAdd(&counts[m], 1);
}

__global__ __launch_bounds__(1024) void k_scan(const int* __restrict__ counts,
                                               int* __restrict__ rowptr, int* __restrict__ cursor){
  __shared__ int part[1024];
  int t = threadIdx.x;
  int local[6];
  int s = 0, base = t*6;
  for (int q = 0; q < 6; q++){
    int i = base + q; int c = (i < NN) ? counts[i] : 0;
    local[q] = s; s += c;
  }
  part[t] = s; __syncthreads();
  for (int off = 1; off < 1024; off <<= 1){
    int v = (t >= off) ? part[t-off] : 0;
    __syncthreads();
    part[t] += v;
    __syncthreads();
  }
  int excl = (t > 0) ? part[t-1] : 0;
  for (int q = 0; q < 6; q++){
    int i = base + q;
    if (i < NN){ int p = excl + local[q]; rowptr[i] = p; cursor[i] = p; }
  }
  if (t == 1023) rowptr[NN] = part[1023];
}

__global__ void k_fill(const int* __restrict__ topcols, const float* __restrict__ topvals,
                       const float* __restrict__ dis, int* __restrict__ cursor,
                       int* __restrict__ csr_src, float* __restrict__ csr_w){
  int id = blockIdx.x*blockDim.x + threadIdx.x;
  if (id >= NEDGE) return;
  int n = id / (KTOP+1), e = id % (KTOP+1);
  int m; float v;
  if (e < KTOP){ m = topcols[n*KTOP+e]; v = topvals[n*KTOP+e]; }
  else { m = n; v = 1.0f; }
  float w = v * dis[n] * dis[m];
  int pos = atomicAdd(&cursor[m], 1);
  csr_src[pos] = n; csr_w[pos] = w;
}

// ---------------- scatter (last occurrence wins, numpy semantics) ----------------
__global__ void k_winner(const int* __restrict__ idx, int* __restrict__ winner){
  int s = blockIdx.x*blockDim.x + threadIdx.x;
  if (s >= NSUB) return;
  atomicMax(&winner[idx[s]], s);
}

__global__ void k_h0(const float* __restrict__ subset, const float* __restrict__ uinit,
                     const int* __restrict__ winner, u16* __restrict__ h){
  int id = blockIdx.x*blockDim.x + threadIdx.x;
  if (id >= ROWS*DD) return;
  int c = id % DD; int bn = id / DD; int n = bn % NN; int b = bn / NN;
  int w = winner[n];
  float v = (w >= 0) ? subset[((size_t)b*NSUB + w)*DD + c] : uinit[c];
  h[id] = f2b(v);
}

// ---------------- weight transpose/convert: wbf[mat][n][k] = W[k][n] ----------------
__global__ void k_wprep(const float* __restrict__ mlp_w, const float* __restrict__ gate_w,
                        const float* __restrict__ diff_w, u16* __restrict__ wbf){
  int id = blockIdx.x*blockDim.x + threadIdx.x;
  if (id >= NLAY*5*WMAT) return;
  int mat = id / WMAT, rem = id % WMAT;
  int n = rem / DD, k = rem % DD;
  int layer = mat / 5, which = mat % 5;
  float v;
  if (which == 0)      v = mlp_w [((size_t)layer*DD   + k      )*DD + n];
  else if (which == 1) v = gate_w[((size_t)layer*2*DD + k      )*DD + n];
  else if (which == 2) v = gate_w[((size_t)layer*2*DD + DD + k )*DD + n];
  else if (which == 3) v = diff_w[((size_t)layer*2*DD + k      )*DD + n];
  else                 v = diff_w[((size_t)layer*2*DD + DD + k )*DD + n];
  wbf[id] = f2b(v);
}

// ---------------- SpMM: agg[b,m,:] = sum_in-edges w * h[b,src,:] ----------------
__global__ __launch_bounds__(192) void k_spmm(const u16* __restrict__ h, const int* __restrict__ rowptr,
                       const int* __restrict__ csr_src, const float* __restrict__ csr_w,
                       u16* __restrict__ agg){
  __shared__ int s_src[256]; __shared__ float s_w[256];
  int m = blockIdx.x; int c = threadIdx.x;
  int beg = rowptr[m], end = rowptr[m+1];
  float acc[BB];
  #pragma unroll
  for (int b = 0; b < BB; b++) acc[b] = 0.f;
  for (int base = beg; base < end; base += 256){
    int cnt = end - base; if (cnt > 256) cnt = 256;
    __syncthreads();
    for (int e = threadIdx.x; e < cnt; e += 192){ s_src[e] = csr_src[base+e]; s_w[e] = csr_w[base+e]; }
    __syncthreads();
    for (int e = 0; e < cnt; e++){
      int src = s_src[e]; float w = s_w[e];
      const u16* hp = h + (size_t)src*DD + c;
      #pragma unroll
      for (int b = 0; b < BB; b++) acc[b] += w * b2f(hp[(size_t)b*NN*DD]);
    }
  }
  #pragma unroll
  for (int b = 0; b < BB; b++) agg[((size_t)b*NN + m)*DD + c] = f2b(acc[b]);
}

// ---------------- fused layer: hn / gate / highway / diffusion (bf16 MFMA) ----------------
// Wave w owns col-tiles {3w,3w+1,3w+2}; B fragments register-resident per stage.
#define LP 200  // LDS row pitch in bf16 elems (192 + 8 pad)
__global__ __launch_bounds__(256, 2) void k_layer(u16* __restrict__ h, const u16* __restrict__ agg,
                        const u16* __restrict__ wl, const float* __restrict__ mb,
                        const float* __restrict__ gb, const float* __restrict__ db){
  __shared__ u16 Ah[64*LP];
  __shared__ u16 Ax[64*LP];
  const int tid = threadIdx.x, lane = tid & 63, wave = tid >> 6;
  const int q = lane >> 4, ln = lane & 15;
  const int row0 = blockIdx.x*64;

  for (int i = tid; i < 64*24; i += 256){
    int r = i/24, c0 = i%24;
    ((uint4*)&Ah[r*LP])[c0] = ((const uint4*)h  )[(size_t)(row0+r)*24 + c0];
    ((uint4*)&Ax[r*LP])[c0] = ((const uint4*)agg)[(size_t)(row0+r)*24 + c0];
  }
  __syncthreads();

  const u16 *Wm = wl, *G1 = wl + WMAT, *G2 = wl + 2*WMAT, *D1 = wl + 3*WMAT, *D2 = wl + 4*WMAT;

  f32x4 acc[4][3];
  bf16x8 Bf[6][3];

  auto loadB = [&](const u16* wp){
    #pragma unroll
    for (int kk = 0; kk < 6; kk++)
      #pragma unroll
      for (int ntl = 0; ntl < 3; ntl++){
        int nt = wave*3 + ntl;
        Bf[kk][ntl] = *(const bf16x8*)&wp[(size_t)(nt*16 + ln)*DD + kk*32 + q*8];
      }
  };
  auto gemm = [&](const u16* Al){
    #pragma unroll
    for (int kk = 0; kk < 6; kk++){
      bf16x8 a[4];
      #pragma unroll
      for (int rt = 0; rt < 4; rt++)
        a[rt] = *(const bf16x8*)&Al[(rt*16 + ln)*LP + kk*32 + q*8];
      #pragma unroll
      for (int rt = 0; rt < 4; rt++)
        #pragma unroll
        for (int ntl = 0; ntl < 3; ntl++)
          acc[rt][ntl] = __builtin_amdgcn_mfma_f32_16x16x32_bf16(a[rt], Bf[kk][ntl], acc[rt][ntl], 0, 0, 0);
    }
  };
  auto zacc = [&](){
    #pragma unroll
    for (int rt = 0; rt < 4; rt++)
      #pragma unroll
      for (int ntl = 0; ntl < 3; ntl++)
        acc[rt][ntl] = (f32x4){0.f, 0.f, 0.f, 0.f};
  };

  // ---- stage 1: hn = agg @ Wm + mb  -> Ax
  zacc(); loadB(Wm); gemm(Ax);
  __syncthreads();
  #pragma unroll
  for (int ntl = 0; ntl < 3; ntl++){
    int col = (wave*3 + ntl)*16 + ln; float bias = mb[col];
    #pragma unroll
    for (int rt = 0; rt < 4; rt++)
      #pragma unroll
      for (int r = 0; r < 4; r++)
        Ax[(rt*16 + q*4 + r)*LP + col] = f2b(acc[rt][ntl][r] + bias);
  }
  __syncthreads();

  // ---- stage 2: g = sigmoid(h@G1 + hn@G2 + gb); lo = g*hn + (1-g)*h -> Ax
  zacc(); loadB(G1); gemm(Ah); loadB(G2); gemm(Ax);
  __syncthreads();
  #pragma unroll
  for (int ntl = 0; ntl < 3; ntl++){
    int col = (wave*3 + ntl)*16 + ln; float bias = gb[col];
    #pragma unroll
    for (int rt = 0; rt < 4; rt++)
      #pragma unroll
      for (int r = 0; r < 4; r++){
        int off = (rt*16 + q*4 + r)*LP + col;
        float g = 1.f/(1.f + expf(-(acc[rt][ntl][r] + bias)));
        float hv = b2f(Ah[off]), hnv = b2f(Ax[off]);
        Ax[off] = f2b(g*hnv + (1.f - g)*hv);
      }
  }
  __syncthreads();

  // ---- stage 3: dg = sigmoid(h@D1 + lo@D2 + db); h' = dg*lo + (1-dg)*h -> global
  zacc(); loadB(D1); gemm(Ah); loadB(D2); gemm(Ax);
  #pragma unroll
  for (int ntl = 0; ntl < 3; ntl++){
    int col = (wave*3 + ntl)*16 + ln; float bias = db[col];
    #pragma unroll
    for (int rt = 0; rt < 4; rt++)
      #pragma unroll
      for (int r = 0; r < 4; r++){
        int row = rt*16 + q*4 + r; int off = row*LP + col;
        float dg = 1.f/(1.f + expf(-(acc[rt][ntl][r] + bias)));
        float lov = b2f(Ax[off]), hv = b2f(Ah[off]);
        h[(size_t)(row0 + row)*DD + col] = f2b(dg*lov + (1.f - dg)*hv);
      }
  }
}

// ---------------- final confidence fusion (fp32 h0 path kept exact) ----------------
__global__ void k_final(const u16* __restrict__ h, const float* __restrict__ subset,
                        const int* __restrict__ winner, const float* __restrict__ ca_p,
                        float* __restrict__ out){
  int id = blockIdx.x*blockDim.x + threadIdx.x;
  if (id >= ROWS*DD) return;
  int c = id % DD; int bn = id / DD; int n = bn % NN; int b = bn / NN;
  float ca = ca_p[0];
  int w = winner[n];
  float hv = b2f(h[id]);
  float o;
  if (w >= 0){
    float h0 = subset[((size_t)b*NSUB + w)*DD + c];
    o = (1.0f - ca)*h0 + ca*hv;
  } else {
    o = hv;
  }
  out[id] = o;
}

extern "C" void kernel_launch(void* const* d_in, const int* in_sizes, int n_in,
                              void* d_out, int out_size, void* d_ws, size_t ws_size,
                              hipStream_t stream) {
  const float* subset = (const float*)d_in[0];
  const int*   idxs   = (const int*)  d_in[1];
  const float* emb1   = (const float*)d_in[2];
  const float* emb2   = (const float*)d_in[3];
  const float* l1w    = (const float*)d_in[4];
  const float* l1b    = (const float*)d_in[5];
  const float* l2w    = (const float*)d_in[6];
  const float* l2b    = (const float*)d_in[7];
  const float* uinit  = (const float*)d_in[8];
  const float* mlp_w  = (const float*)d_in[9];
  const float* mlp_b  = (const float*)d_in[10];
  const float* gate_w = (const float*)d_in[11];
  const float* gate_b = (const float*)d_in[12];
  const float* diff_w = (const float*)d_in[13];
  const float* diff_b = (const float*)d_in[14];
  const float* ca     = (const float*)d_in[15];
  float* out = (float*)d_out;

  char* base = (char*)d_ws; size_t off = 0;
  auto alloc = [&](size_t b)->void*{ void* p = base + off; off += b; off = (off + 255) & ~(size_t)255; return p; };
  float* U       = (float*)alloc((size_t)NN*80*4);
  float* V       = (float*)alloc((size_t)NN*80*4);
  u16*   h       = (u16*)  alloc((size_t)ROWS*DD*2);
  u16*   agg     = (u16*)  alloc((size_t)ROWS*DD*2);
  u16*   wbf     = (u16*)  alloc((size_t)NLAY*5*WMAT*2);
  int*   topcols = (int*)  alloc((size_t)NN*KTOP*4);
  float* topvals = (float*)alloc((size_t)NN*KTOP*4);
  float* dis     = (float*)alloc((size_t)NN*4);
  int*   winner  = (int*)  alloc((size_t)NN*4);
  int*   counts  = (int*)  alloc((size_t)NN*4);
  int*   rowptr  = (int*)  alloc((size_t)(NN+1)*4);
  int*   cursor  = (int*)  alloc((size_t)NN*4);
  int*   csr_src = (int*)  alloc((size_t)NEDGE*4);
  float* csr_w   = (float*)alloc((size_t)NEDGE*4);
  float* ptv     = (float*)alloc((size_t)NSTRIP*RCAP*KTOP*4);
  int*   ptc     = (int*)  alloc((size_t)NSTRIP*RCAP*KTOP*4);

  // 1. graph constructor tables
  k_prep_uv<<<(NN*GD + 255)/256, 256, 0, stream>>>(emb1, emb2, l1w, l1b, l2w, l2b, U, V);

  // 2. fused score + top-k, then strip merge
  dim3 gs(94, NSTRIP);
  k_scoretopk<<<gs, 256, 0, stream>>>(U, V, ptv, ptc);
  k_mergetopk<<<(NN + 255)/256, 256, 0, stream>>>(ptv, ptc, topcols, topvals, dis);

  // 3. CSR of transpose graph
  hipMemsetAsync(counts, 0, (size_t)NN*4, stream);
  k_count<<<(NEDGE + 255)/256, 256, 0, stream>>>(topcols, counts);
  k_scan<<<1, 1024, 0, stream>>>(counts, rowptr, cursor);
  k_fill<<<(NEDGE + 255)/256, 256, 0, stream>>>(topcols, topvals, dis, cursor, csr_src, csr_w);

  // 4. scatter init
  hipMemsetAsync(winner, 0xFF, (size_t)NN*4, stream);
  k_winner<<<(NSUB + 255)/256, 256, 0, stream>>>(idxs, winner);
  k_h0<<<(ROWS*DD + 255)/256, 256, 0, stream>>>(subset, uinit, winner, h);

  // 5. weights -> bf16 transposed
  k_wprep<<<(NLAY*5*WMAT + 255)/256, 256, 0, stream>>>(mlp_w, gate_w, diff_w, wbf);

  // 6. layers
  for (int l = 0; l < NLAY; l++){
    k_spmm<<<NN, 192, 0, stream>>>(h, rowptr, csr_src, csr_w, agg);
    k_layer<<<ROWS/64, 256, 0, stream>>>(h, agg, wbf + (size_t)l*5*WMAT,
                                         mlp_b + l*DD, gate_b + l*DD, diff_b + l*DD);
  }

  // 7. confidence fusion
  k_final<<<(ROWS*DD + 255)/256, 256, 0, stream>>>(h, subset, winner, ca, out);
}

// Round 4
// 553.993 us; speedup vs baseline: 1.9628x; 1.1726x over previous
//
#include <hip/hip_runtime.h>
#include <math.h>

#define NN 6000
#define NSUB 4500
#define BB 8
#define DD 192
#define GD 40
#define KTOP 10
#define NLAY 3
#define ROWS (BB*NN)          // 48000
#define NEDGE (NN*(KTOP+1))   // 66000
#define WMAT (DD*DD)          // 36864
#define NSTRIP 8
#define SCOLS 750             // cols per strip (8*750 = 6000)
#define NTILE 12              // ceil(750/64)
#define RCAP 6016             // padded row capacity for partials
#define SP 100                // LDS row pitch in f16 elems (50 dwords, odd-ish stride -> 2-way max)

typedef unsigned short u16;
typedef unsigned int u32;
typedef __attribute__((ext_vector_type(8))) short bf16x8;
typedef __attribute__((ext_vector_type(8))) _Float16 f16x8;
typedef __attribute__((ext_vector_type(4))) float f32x4;

__device__ __forceinline__ u16 f2b(float x){
  u32 u = __float_as_uint(x);
  u32 r = (u + 0x7fffu + ((u >> 16) & 1u)) >> 16;
  return (u16)r;
}
__device__ __forceinline__ float b2f(u16 h){
  u32 u = ((u32)h) << 16; return __uint_as_float(u);
}
// order-preserving monotone float->uint key
__device__ __forceinline__ u32 fkey(float f){
  u32 b = __float_as_uint(f);
  return (b & 0x80000000u) ? ~b : (b | 0x80000000u);
}
__device__ __forceinline__ u32 packh2(float a, float b){
  _Float16 ha = (_Float16)a, hb = (_Float16)b;
  u16 ua = __builtin_bit_cast(u16, ha), ub = __builtin_bit_cast(u16, hb);
  return (u32)ua | ((u32)ub << 16);
}
__device__ __forceinline__ u32 packl2(float a, float b){
  _Float16 ha = (_Float16)a, hb = (_Float16)b;
  _Float16 la = (_Float16)(a - (float)ha), lb = (_Float16)(b - (float)hb);
  u16 ua = __builtin_bit_cast(u16, la), ub = __builtin_bit_cast(u16, lb);
  return (u32)ua | ((u32)ub << 16);
}
// load 8 consecutive f16 (16B logical) as two 8B chunks (8B-aligned)
__device__ __forceinline__ f16x8 ldfrag(const u16* p){
  union { f16x8 v; double d[2]; } u;
  const double* q = (const double*)p;
  u.d[0] = q[0]; u.d[1] = q[1];
  return u.v;
}

// ---------------- graph-constructor prep: U,V tables ----------------
__global__ void k_prep_uv(const float* __restrict__ emb1, const float* __restrict__ emb2,
                          const float* __restrict__ w1, const float* __restrict__ b1,
                          const float* __restrict__ w2, const float* __restrict__ b2,
                          float* __restrict__ U, float* __restrict__ V){
  int id = blockIdx.x*blockDim.x + threadIdx.x;
  if (id >= NN*GD) return;
  int i = id / GD, g = id % GD;
  float s1 = b1[g], s2 = b2[g];
  for (int k = 0; k < GD; k++){
    s1 += emb1[i*GD+k]*w1[k*GD+g];
    s2 += emb2[i*GD+k]*w2[k*GD+g];
  }
  float n1 = tanhf(3.0f*s1), n2 = tanhf(3.0f*s2);
  U[i*80+g]    = 0.5f*n1;  U[i*80+40+g] = 0.5f*n2;
  V[i*80+g]    = n2;       V[i*80+40+g] = n1;
}

// ---------------- fused score (MFMA f16-split) + register top-k ----------------
// Block: 64 rows (wave w owns rows 16w+ln) x 750-col strip, 12 tiles of 64 cols.
// Score tile computed transposed: mfma(A=V-frag, B=U-frag) -> lane holds one row.
__global__ __launch_bounds__(256, 3) void k_scoretopk(const float* __restrict__ U, const float* __restrict__ V,
                          float* __restrict__ ptv, int* __restrict__ ptc){
  __shared__ u32 Uarr[64*SP];       // Uh | Ul  (u16 elems, 64 rows x pitch SP each)
  __shared__ u32 Varr[64*SP];       // Vh | Vl
  __shared__ u32 rowthr[64];
  u16* Uh = (u16*)Uarr;  u16* Ul = Uh + 64*SP;
  u16* Vh = (u16*)Varr;  u16* Vl = Vh + 64*SP;

  const int tid = threadIdx.x, lane = tid & 63, wave = tid >> 6;
  const int q = lane >> 4, ln = lane & 15;
  const int r0 = blockIdx.x*64;
  const int y  = blockIdx.y;
  const int cstart = y*SCOLS, cend = cstart + SCOLS;
  const float NINF = -__builtin_inff();
  const int lrow = wave*16 + ln;

  // ---- stage U rows (96 elems, k>=80 zero) as f16 hi/lo ----
  for (int idx = tid; idx < 64*24; idx += 256){
    int r = idx & 63, c4 = idx >> 6;        // c4: 0..23 (4 elems each)
    float4 u = {0.f,0.f,0.f,0.f};
    if (c4 < 20){
      int gr = r0 + r; if (gr > NN-1) gr = NN-1;
      u = *(const float4*)&U[(size_t)gr*80 + c4*4];
    }
    Uarr[r*50 + c4*2    ] = packh2(u.x, u.y);
    Uarr[r*50 + c4*2 + 1] = packh2(u.z, u.w);
    ((u32*)Ul)[r*50 + c4*2    ] = packl2(u.x, u.y);
    ((u32*)Ul)[r*50 + c4*2 + 1] = packl2(u.z, u.w);
  }
  if (tid < 64) rowthr[tid] = 0u;
  __syncthreads();

  // ---- preload U fragments (rows fixed per lane) into registers ----
  f16x8 Uhf[3], Ulf[3];
  #pragma unroll
  for (int ks = 0; ks < 3; ks++){
    Uhf[ks] = ldfrag(&Uh[lrow*SP + ks*32 + q*8]);
    Ulf[ks] = ldfrag(&Ul[lrow*SP + ks*32 + q*8]);
  }

  float tv[10]; int ti[10];
  #pragma unroll
  for (int s = 0; s < 10; s++){ tv[s] = NINF; ti[s] = NN; }

  for (int t = 0; t < NTILE; t++){
    int cb = cstart + t*64;
    __syncthreads();   // prior tile's V-frag reads complete
    for (int idx = tid; idx < 64*24; idx += 256){
      int r = idx & 63, c4 = idx >> 6;
      float4 v = {0.f,0.f,0.f,0.f};
      if (c4 < 20){
        int gc = cb + r; if (gc > NN-1) gc = NN-1;
        v = *(const float4*)&V[(size_t)gc*80 + c4*4];
      }
      Varr[r*50 + c4*2    ] = packh2(v.x, v.y);
      Varr[r*50 + c4*2 + 1] = packh2(v.z, v.w);
      ((u32*)Vl)[r*50 + c4*2    ] = packl2(v.x, v.y);
      ((u32*)Vl)[r*50 + c4*2 + 1] = packl2(v.z, v.w);
    }
    __syncthreads();

    f32x4 acc[4];
    #pragma unroll
    for (int ch = 0; ch < 4; ch++) acc[ch] = (f32x4){0.f,0.f,0.f,0.f};
    #pragma unroll
    for (int ks = 0; ks < 3; ks++){
      #pragma unroll
      for (int ch = 0; ch < 4; ch++){
        f16x8 vh = ldfrag(&Vh[(ch*16 + ln)*SP + ks*32 + q*8]);
        f16x8 vl = ldfrag(&Vl[(ch*16 + ln)*SP + ks*32 + q*8]);
        acc[ch] = __builtin_amdgcn_mfma_f32_16x16x32_f16(vh, Uhf[ks], acc[ch], 0, 0, 0);
        acc[ch] = __builtin_amdgcn_mfma_f32_16x16x32_f16(vh, Ulf[ks], acc[ch], 0, 0, 0);
        acc[ch] = __builtin_amdgcn_mfma_f32_16x16x32_f16(vl, Uhf[ks], acc[ch], 0, 0, 0);
      }
    }

    // ---- insert: lane's 16 scores all belong to row lrow ----
    u32 Treg = rowthr[lrow];
    #pragma unroll
    for (int ch = 0; ch < 4; ch++){
      #pragma unroll
      for (int rg = 0; rg < 4; rg++){
        int j = cb + ch*16 + q*4 + rg;
        float v = acc[ch][rg];
        u32 uk = fkey(v);
        if (j < cend && uk > Treg && v > tv[9]){
          bool b[9];
          #pragma unroll
          for (int k = 0; k < 9; k++) b[k] = v > tv[k];
          #pragma unroll
          for (int k = 9; k >= 1; k--){
            bool bh = b[k-1];
            bool bk = (k == 9) ? true : b[k];
            tv[k] = bh ? tv[k-1] : (bk ? v : tv[k]);
            ti[k] = bh ? ti[k-1] : (bk ? j : ti[k]);
          }
          if (b[0]){ tv[0] = v; ti[0] = j; }
          u32 k9 = fkey(tv[9]);
          if (k9 > Treg) Treg = k9;
          atomicMax(&rowthr[lrow], k9);
        }
      }
    }
  }

  // ---- per-block merge of the 4 quad lists per row (overlay on Uarr) ----
  __syncthreads();
  float* candv = (float*)Uarr;                 // 64*41 floats
  int*   candi = (int*)(Uarr + 64*41);         // 64*41 ints (total 20992 B <= 25600 B)
  #pragma unroll
  for (int s = 0; s < 10; s++){
    candv[lrow*41 + q*10 + s] = tv[s];
    candi[lrow*41 + q*10 + s] = ti[s];
  }
  __syncthreads();
  if (tid < 64 && r0 + tid < NN){
    int row = tid;
    u32 P = 0;  // 4 x 8-bit pointers
    for (int s = 0; s < 10; s++){
      float bv = NINF; int bi = NN; int by = 0;
      #pragma unroll
      for (int g = 0; g < 4; g++){
        u32 pg = (P >> (8*g)) & 255u;
        u32 pc = pg < 9u ? pg : 9u;
        float v = candv[row*41 + g*10 + pc];
        int  jj = candi[row*41 + g*10 + pc];
        if (pg >= 10u){ v = NINF; jj = NN; }
        if (v > bv || (v == bv && jj < bi)){ bv = v; bi = jj; by = g; }
      }
      P += (1u << (8*by));
      size_t o = ((size_t)y*RCAP + r0 + row)*10 + s;
      ptv[o] = bv; ptc[o] = bi;
    }
  }
}

// ---------------- merge 8 strip partials -> final topk + softplus + dis ----------------
__global__ void k_mergetopk(const float* __restrict__ ptv, const int* __restrict__ ptc,
                            int* __restrict__ topcols, float* __restrict__ topvals,
                            float* __restrict__ dis){
  int r = blockIdx.x*blockDim.x + threadIdx.x;
  if (r >= NN) return;
  const float NINF = -__builtin_inff();
  unsigned long long P = 0;  // 8 x 8-bit pointers
  float d = 1.0f;
  for (int s = 0; s < 10; s++){
    float bv = NINF; int bi = NN; int by = 0;
    #pragma unroll
    for (int g = 0; g < 8; g++){
      u32 pg = (u32)((P >> (8*g)) & 255u);
      u32 pc = pg < 9u ? pg : 9u;
      size_t o = ((size_t)g*RCAP + r)*10 + pc;
      float v = ptv[o]; int jj = ptc[o];
      if (pg >= 10u){ v = NINF; jj = NN; }
      if (v > bv || (v == bv && jj < bi)){ bv = v; bi = jj; by = g; }
    }
    P += (1ull << (8*by));
    float sp = (bv > 20.f) ? bv : log1pf(expf(bv));
    float a = sp - 0.5f; if (a < 0.f) a = 0.f;
    topvals[r*KTOP + s] = a; topcols[r*KTOP + s] = bi;
    d += a;
  }
  dis[r] = rsqrtf(d);
}

// ---------------- CSR (transpose graph) build ----------------
__global__ void k_count(const int* __restrict__ topcols, int* __restrict__ counts){
  int id = blockIdx.x*blockDim.x + threadIdx.x;
  if (id >= NEDGE) return;
  int n = id / (KTOP+1), e = id % (KTOP+1);
  int m = (e < KTOP) ? topcols[n*KTOP+e] : n;
  atomicAdd(&counts[m], 1);
}

__global__ __launch_bounds__(1024) void k_scan(const int* __restrict__ counts,
                                               int* __restrict__ rowptr, int* __restrict__ cursor){
  __shared__ int part[1024];
  int t = threadIdx.x;
  int local[6];
  int s = 0, base = t*6;
  for (int q = 0; q < 6; q++){
    int i = base + q; int c = (i < NN) ? counts[i] : 0;
    local[q] = s; s += c;
  }
  part[t] = s; __syncthreads();
  for (int off = 1; off < 1024; off <<= 1){
    int v = (t >= off) ? part[t-off] : 0;
    __syncthreads();
    part[t] += v;
    __syncthreads();
  }
  int excl = (t > 0) ? part[t-1] : 0;
  for (int q = 0; q < 6; q++){
    int i = base + q;
    if (i < NN){ int p = excl + local[q]; rowptr[i] = p; cursor[i] = p; }
  }
  if (t == 1023) rowptr[NN] = part[1023];
}

__global__ void k_fill(const int* __restrict__ topcols, const float* __restrict__ topvals,
                       const float* __restrict__ dis, int* __restrict__ cursor,
                       int* __restrict__ csr_src, float* __restrict__ csr_w){
  int id = blockIdx.x*blockDim.x + threadIdx.x;
  if (id >= NEDGE) return;
  int n = id / (KTOP+1), e = id % (KTOP+1);
  int m; float v;
  if (e < KTOP){ m = topcols[n*KTOP+e]; v = topvals[n*KTOP+e]; }
  else { m = n; v = 1.0f; }
  float w = v * dis[n] * dis[m];
  int pos = atomicAdd(&cursor[m], 1);
  csr_src[pos] = n; csr_w[pos] = w;
}

// ---------------- scatter (last occurrence wins, numpy semantics) ----------------
__global__ void k_winner(const int* __restrict__ idx, int* __restrict__ winner){
  int s = blockIdx.x*blockDim.x + threadIdx.x;
  if (s >= NSUB) return;
  atomicMax(&winner[idx[s]], s);
}

__global__ void k_h0(const float* __restrict__ subset, const float* __restrict__ uinit,
                     const int* __restrict__ winner, u16* __restrict__ h){
  int id = blockIdx.x*blockDim.x + threadIdx.x;
  if (id >= ROWS*DD) return;
  int c = id % DD; int bn = id / DD; int n = bn % NN; int b = bn / NN;
  int w = winner[n];
  float v = (w >= 0) ? subset[((size_t)b*NSUB + w)*DD + c] : uinit[c];
  h[id] = f2b(v);
}

// ---------------- weight transpose/convert: wbf[mat][n][k] = W[k][n] ----------------
__global__ void k_wprep(const float* __restrict__ mlp_w, const float* __restrict__ gate_w,
                        const float* __restrict__ diff_w, u16* __restrict__ wbf){
  int id = blockIdx.x*blockDim.x + threadIdx.x;
  if (id >= NLAY*5*WMAT) return;
  int mat = id / WMAT, rem = id % WMAT;
  int n = rem / DD, k = rem % DD;
  int layer = mat / 5, which = mat % 5;
  float v;
  if (which == 0)      v = mlp_w [((size_t)layer*DD   + k      )*DD + n];
  else if (which == 1) v = gate_w[((size_t)layer*2*DD + k      )*DD + n];
  else if (which == 2) v = gate_w[((size_t)layer*2*DD + DD + k )*DD + n];
  else if (which == 3) v = diff_w[((size_t)layer*2*DD + k      )*DD + n];
  else                 v = diff_w[((size_t)layer*2*DD + DD + k )*DD + n];
  wbf[id] = f2b(v);
}

// ---------------- SpMM: agg[b,m,:] = sum_in-edges w * h[b,src,:] ----------------
__global__ __launch_bounds__(192) void k_spmm(const u16* __restrict__ h, const int* __restrict__ rowptr,
                       const int* __restrict__ csr_src, const float* __restrict__ csr_w,
                       u16* __restrict__ agg){
  __shared__ int s_src[256]; __shared__ float s_w[256];
  int m = blockIdx.x; int c = threadIdx.x;
  int beg = rowptr[m], end = rowptr[m+1];
  float acc[BB];
  #pragma unroll
  for (int b = 0; b < BB; b++) acc[b] = 0.f;
  for (int base = beg; base < end; base += 256){
    int cnt = end - base; if (cnt > 256) cnt = 256;
    __syncthreads();
    for (int e = threadIdx.x; e < cnt; e += 192){ s_src[e] = csr_src[base+e]; s_w[e] = csr_w[base+e]; }
    __syncthreads();
    for (int e = 0; e < cnt; e++){
      int src = s_src[e]; float w = s_w[e];
      const u16* hp = h + (size_t)src*DD + c;
      #pragma unroll
      for (int b = 0; b < BB; b++) acc[b] += w * b2f(hp[(size_t)b*NN*DD]);
    }
  }
  #pragma unroll
  for (int b = 0; b < BB; b++) agg[((size_t)b*NN + m)*DD + c] = f2b(acc[b]);
}

// ---------------- fused layer: hn / gate / highway / diffusion (bf16 MFMA) ----------------
// Wave w owns col-tiles {3w,3w+1,3w+2}; B fragments register-resident per stage.
#define LP 200  // LDS row pitch in bf16 elems (192 + 8 pad)
__global__ __launch_bounds__(256, 2) void k_layer(u16* __restrict__ h, const u16* __restrict__ agg,
                        const u16* __restrict__ wl, const float* __restrict__ mb,
                        const float* __restrict__ gb, const float* __restrict__ db){
  __shared__ u16 Ah[64*LP];
  __shared__ u16 Ax[64*LP];
  const int tid = threadIdx.x, lane = tid & 63, wave = tid >> 6;
  const int q = lane >> 4, ln = lane & 15;
  const int row0 = blockIdx.x*64;

  for (int i = tid; i < 64*24; i += 256){
    int r = i/24, c0 = i%24;
    ((uint4*)&Ah[r*LP])[c0] = ((const uint4*)h  )[(size_t)(row0+r)*24 + c0];
    ((uint4*)&Ax[r*LP])[c0] = ((const uint4*)agg)[(size_t)(row0+r)*24 + c0];
  }
  __syncthreads();

  const u16 *Wm = wl, *G1 = wl + WMAT, *G2 = wl + 2*WMAT, *D1 = wl + 3*WMAT, *D2 = wl + 4*WMAT;

  f32x4 acc[4][3];
  bf16x8 Bf[6][3];

  auto loadB = [&](const u16* wp){
    #pragma unroll
    for (int kk = 0; kk < 6; kk++)
      #pragma unroll
      for (int ntl = 0; ntl < 3; ntl++){
        int nt = wave*3 + ntl;
        Bf[kk][ntl] = *(const bf16x8*)&wp[(size_t)(nt*16 + ln)*DD + kk*32 + q*8];
      }
  };
  auto gemm = [&](const u16* Al){
    #pragma unroll
    for (int kk = 0; kk < 6; kk++){
      bf16x8 a[4];
      #pragma unroll
      for (int rt = 0; rt < 4; rt++)
        a[rt] = *(const bf16x8*)&Al[(rt*16 + ln)*LP + kk*32 + q*8];
      #pragma unroll
      for (int rt = 0; rt < 4; rt++)
        #pragma unroll
        for (int ntl = 0; ntl < 3; ntl++)
          acc[rt][ntl] = __builtin_amdgcn_mfma_f32_16x16x32_bf16(a[rt], Bf[kk][ntl], acc[rt][ntl], 0, 0, 0);
    }
  };
  auto zacc = [&](){
    #pragma unroll
    for (int rt = 0; rt < 4; rt++)
      #pragma unroll
      for (int ntl = 0; ntl < 3; ntl++)
        acc[rt][ntl] = (f32x4){0.f, 0.f, 0.f, 0.f};
  };

  // ---- stage 1: hn = agg @ Wm + mb  -> Ax
  zacc(); loadB(Wm); gemm(Ax);
  __syncthreads();
  #pragma unroll
  for (int ntl = 0; ntl < 3; ntl++){
    int col = (wave*3 + ntl)*16 + ln; float bias = mb[col];
    #pragma unroll
    for (int rt = 0; rt < 4; rt++)
      #pragma unroll
      for (int r = 0; r < 4; r++)
        Ax[(rt*16 + q*4 + r)*LP + col] = f2b(acc[rt][ntl][r] + bias);
  }
  __syncthreads();

  // ---- stage 2: g = sigmoid(h@G1 + hn@G2 + gb); lo = g*hn + (1-g)*h -> Ax
  zacc(); loadB(G1); gemm(Ah); loadB(G2); gemm(Ax);
  __syncthreads();
  #pragma unroll
  for (int ntl = 0; ntl < 3; ntl++){
    int col = (wave*3 + ntl)*16 + ln; float bias = gb[col];
    #pragma unroll
    for (int rt = 0; rt < 4; rt++)
      #pragma unroll
      for (int r = 0; r < 4; r++){
        int off = (rt*16 + q*4 + r)*LP + col;
        float g = 1.f/(1.f + expf(-(acc[rt][ntl][r] + bias)));
        float hv = b2f(Ah[off]), hnv = b2f(Ax[off]);
        Ax[off] = f2b(g*hnv + (1.f - g)*hv);
      }
  }
  __syncthreads();

  // ---- stage 3: dg = sigmoid(h@D1 + lo@D2 + db); h' = dg*lo + (1-dg)*h -> global
  zacc(); loadB(D1); gemm(Ah); loadB(D2); gemm(Ax);
  #pragma unroll
  for (int ntl = 0; ntl < 3; ntl++){
    int col = (wave*3 + ntl)*16 + ln; float bias = db[col];
    #pragma unroll
    for (int rt = 0; rt < 4; rt++)
      #pragma unroll
      for (int r = 0; r < 4; r++){
        int row = rt*16 + q*4 + r; int off = row*LP + col;
        float dg = 1.f/(1.f + expf(-(acc[rt][ntl][r] + bias)));
        float lov = b2f(Ax[off]), hv = b2f(Ah[off]);
        h[(size_t)(row0 + row)*DD + col] = f2b(dg*lov + (1.f - dg)*hv);
      }
  }
}

// ---------------- final confidence fusion (fp32 h0 path kept exact) ----------------
__global__ void k_final(const u16* __restrict__ h, const float* __restrict__ subset,
                        const int* __restrict__ winner, const float* __restrict__ ca_p,
                        float* __restrict__ out){
  int id = blockIdx.x*blockDim.x + threadIdx.x;
  if (id >= ROWS*DD) return;
  int c = id % DD; int bn = id / DD; int n = bn % NN; int b = bn / NN;
  float ca = ca_p[0];
  int w = winner[n];
  float hv = b2f(h[id]);
  float o;
  if (w >= 0){
    float h0 = subset[((size_t)b*NSUB + w)*DD + c];
    o = (1.0f - ca)*h0 + ca*hv;
  } else {
    o = hv;
  }
  out[id] = o;
}

extern "C" void kernel_launch(void* const* d_in, const int* in_sizes, int n_in,
                              void* d_out, int out_size, void* d_ws, size_t ws_size,
                              hipStream_t stream) {
  const float* subset = (const float*)d_in[0];
  const int*   idxs   = (const int*)  d_in[1];
  const float* emb1   = (const float*)d_in[2];
  const float* emb2   = (const float*)d_in[3];
  const float* l1w    = (const float*)d_in[4];
  const float* l1b    = (const float*)d_in[5];
  const float* l2w    = (const float*)d_in[6];
  const float* l2b    = (const float*)d_in[7];
  const float* uinit  = (const float*)d_in[8];
  const float* mlp_w  = (const float*)d_in[9];
  const float* mlp_b  = (const float*)d_in[10];
  const float* gate_w = (const float*)d_in[11];
  const float* gate_b = (const float*)d_in[12];
  const float* diff_w = (const float*)d_in[13];
  const float* diff_b = (const float*)d_in[14];
  const float* ca     = (const float*)d_in[15];
  float* out = (float*)d_out;

  char* base = (char*)d_ws; size_t off = 0;
  auto alloc = [&](size_t b)->void*{ void* p = base + off; off += b; off = (off + 255) & ~(size_t)255; return p; };
  float* U       = (float*)alloc((size_t)NN*80*4);
  float* V       = (float*)alloc((size_t)NN*80*4);
  u16*   h       = (u16*)  alloc((size_t)ROWS*DD*2);
  u16*   agg     = (u16*)  alloc((size_t)ROWS*DD*2);
  u16*   wbf     = (u16*)  alloc((size_t)NLAY*5*WMAT*2);
  int*   topcols = (int*)  alloc((size_t)NN*KTOP*4);
  float* topvals = (float*)alloc((size_t)NN*KTOP*4);
  float* dis     = (float*)alloc((size_t)NN*4);
  int*   winner  = (int*)  alloc((size_t)NN*4);
  int*   counts  = (int*)  alloc((size_t)NN*4);
  int*   rowptr  = (int*)  alloc((size_t)(NN+1)*4);
  int*   cursor  = (int*)  alloc((size_t)NN*4);
  int*   csr_src = (int*)  alloc((size_t)NEDGE*4);
  float* csr_w   = (float*)alloc((size_t)NEDGE*4);
  float* ptv     = (float*)alloc((size_t)NSTRIP*RCAP*KTOP*4);
  int*   ptc     = (int*)  alloc((size_t)NSTRIP*RCAP*KTOP*4);

  // 1. graph constructor tables
  k_prep_uv<<<(NN*GD + 255)/256, 256, 0, stream>>>(emb1, emb2, l1w, l1b, l2w, l2b, U, V);

  // 2. fused score + top-k, then strip merge
  dim3 gs(94, NSTRIP);
  k_scoretopk<<<gs, 256, 0, stream>>>(U, V, ptv, ptc);
  k_mergetopk<<<(NN + 255)/256, 256, 0, stream>>>(ptv, ptc, topcols, topvals, dis);

  // 3. CSR of transpose graph
  hipMemsetAsync(counts, 0, (size_t)NN*4, stream);
  k_count<<<(NEDGE + 255)/256, 256, 0, stream>>>(topcols, counts);
  k_scan<<<1, 1024, 0, stream>>>(counts, rowptr, cursor);
  k_fill<<<(NEDGE + 255)/256, 256, 0, stream>>>(topcols, topvals, dis, cursor, csr_src, csr_w);

  // 4. scatter init
  hipMemsetAsync(winner, 0xFF, (size_t)NN*4, stream);
  k_winner<<<(NSUB + 255)/256, 256, 0, stream>>>(idxs, winner);
  k_h0<<<(ROWS*DD + 255)/256, 256, 0, stream>>>(subset, uinit, winner, h);

  // 5. weights -> bf16 transposed
  k_wprep<<<(NLAY*5*WMAT + 255)/256, 256, 0, stream>>>(mlp_w, gate_w, diff_w, wbf);

  // 6. layers
  for (int l = 0; l < NLAY; l++){
    k_spmm<<<NN, 192, 0, stream>>>(h, rowptr, csr_src, csr_w, agg);
    k_layer<<<ROWS/64, 256, 0, stream>>>(h, agg, wbf + (size_t)l*5*WMAT,
                                         mlp_b + l*DD, gate_b + l*DD, diff_b + l*DD);
  }

  // 7. confidence fusion
  k_final<<<(ROWS*DD + 255)/256, 256, 0, stream>>>(h, subset, winner, ca, out);
}

// Round 6
// 505.835 us; speedup vs baseline: 2.1496x; 1.0952x over previous
//
#include <hip/hip_runtime.h>
#include <math.h>

#define NN 6000
#define NSUB 4500
#define BB 8
#define DD 192
#define GD 40
#define KTOP 10
#define NLAY 3
#define ROWS (BB*NN)          // 48000
#define NEDGE (NN*(KTOP+1))   // 66000
#define WMAT (DD*DD)          // 36864
#define NSTRIP 8
#define SCOLS 750             // cols per strip (8*750 = 6000)
#define NTILE 12              // ceil(750/64)
#define RCAP 6016             // padded row capacity for partials
#define KP 96                 // padded K for f16 tables (12 uint4 chunks per row)
#define SP2 104               // LDS row pitch in f16 elems (16B-aligned rows, <=2-way b64)

typedef unsigned short u16;
typedef unsigned int u32;
typedef __attribute__((ext_vector_type(8))) short bf16x8;
typedef __attribute__((ext_vector_type(8))) _Float16 f16x8;
typedef __attribute__((ext_vector_type(4))) float f32x4;

__device__ __forceinline__ u16 f2b(float x){
  u32 u = __float_as_uint(x);
  u32 r = (u + 0x7fffu + ((u >> 16) & 1u)) >> 16;
  return (u16)r;
}
__device__ __forceinline__ float b2f(u16 h){
  u32 u = ((u32)h) << 16; return __uint_as_float(u);
}
// order-preserving monotone float->uint key
__device__ __forceinline__ u32 fkey(float f){
  u32 b = __float_as_uint(f);
  return (b & 0x80000000u) ? ~b : (b | 0x80000000u);
}
__device__ __forceinline__ void wr_hl(u16* __restrict__ H, u16* __restrict__ L, size_t off, float x){
  _Float16 hx = (_Float16)x;
  H[off] = __builtin_bit_cast(u16, hx);
  _Float16 lx = (_Float16)(x - (float)hx);
  L[off] = __builtin_bit_cast(u16, lx);
}
// load 8 consecutive f16 as two 8B chunks (8B-aligned)
__device__ __forceinline__ f16x8 ldfrag(const u16* p){
  union { f16x8 v; double d[2]; } u;
  const double* q = (const double*)p;
  u.d[0] = q[0]; u.d[1] = q[1];
  return u.v;
}

// ---------------- graph-constructor prep: f16 hi/lo tables ----------------
// U[i] = [0.5*nv1_i, 0.5*nv2_i, 0pad], V[j] = [nv2_j, nv1_j, 0pad]  (96 f16 each, hi+lo)
__global__ void k_prep_uv(const float* __restrict__ emb1, const float* __restrict__ emb2,
                          const float* __restrict__ w1, const float* __restrict__ b1,
                          const float* __restrict__ w2, const float* __restrict__ b2,
                          u16* __restrict__ Uh, u16* __restrict__ Ul,
                          u16* __restrict__ Vh, u16* __restrict__ Vl){
  int id = blockIdx.x*blockDim.x + threadIdx.x;
  if (id >= NN*GD) return;
  int i = id / GD, g = id % GD;
  float s1 = b1[g], s2 = b2[g];
  for (int k = 0; k < GD; k++){
    s1 += emb1[i*GD+k]*w1[k*GD+g];
    s2 += emb2[i*GD+k]*w2[k*GD+g];
  }
  float n1 = tanhf(3.0f*s1), n2 = tanhf(3.0f*s2);
  size_t base = (size_t)i*KP;
  wr_hl(Uh, Ul, base + g,      0.5f*n1);
  wr_hl(Uh, Ul, base + 40 + g, 0.5f*n2);
  wr_hl(Vh, Vl, base + g,      n2);
  wr_hl(Vh, Vl, base + 40 + g, n1);
  if (g < 16){
    Uh[base+80+g] = 0; Ul[base+80+g] = 0;
    Vh[base+80+g] = 0; Vl[base+80+g] = 0;
  }
}

// ---------------- fused score (MFMA f16-split) + register top-k ----------------
// Block: 64 rows (wave w owns row 16w+ln) x 750-col strip, 12 tiles of 64 cols.
// Score tile computed transposed: mfma(A=V-frag, B=U-frag) -> lane holds one row.
__global__ __launch_bounds__(256, 3) void k_scoretopk(
                          const u16* __restrict__ Uh, const u16* __restrict__ Ul,
                          const u16* __restrict__ Vh, const u16* __restrict__ Vl,
                          float* __restrict__ ptv, int* __restrict__ ptc){
  __shared__ u16 Us[2*64*SP2];      // hi | lo
  __shared__ u16 Vs[2*64*SP2];
  __shared__ u32 rowthr[64];
  u16* Ushi = Us;        u16* Uslo = Us + 64*SP2;
  u16* Vshi = Vs;        u16* Vslo = Vs + 64*SP2;

  const int tid = threadIdx.x, lane = tid & 63, wave = tid >> 6;
  const int q = lane >> 4, ln = lane & 15;
  const int r0 = blockIdx.x*64;
  const int y  = blockIdx.y;
  const int cstart = y*SCOLS, cend = cstart + SCOLS;
  const float NINF = -__builtin_inff();
  const int lrow = wave*16 + ln;

  // ---- stage U rows once (pure copy; 12 x uint4 per row per plane) ----
  for (int idx = tid; idx < 64*12; idx += 256){
    int r = idx/12, c4 = idx%12;
    int gr = r0 + r; if (gr > NN-1) gr = NN-1;
    *(uint4*)&Ushi[r*SP2 + c4*8] = *(const uint4*)&Uh[(size_t)gr*KP + c4*8];
    *(uint4*)&Uslo[r*SP2 + c4*8] = *(const uint4*)&Ul[(size_t)gr*KP + c4*8];
  }
  if (tid < 64) rowthr[tid] = 0u;
  __syncthreads();

  // ---- preload U fragments (rows fixed per lane) into registers ----
  f16x8 Uhf[3], Ulf[3];
  #pragma unroll
  for (int ks = 0; ks < 3; ks++){
    Uhf[ks] = ldfrag(&Ushi[lrow*SP2 + ks*32 + q*8]);
    Ulf[ks] = ldfrag(&Uslo[lrow*SP2 + ks*32 + q*8]);
  }

  float tv[10]; int ti[10];
  #pragma unroll
  for (int s = 0; s < 10; s++){ tv[s] = NINF; ti[s] = NN; }

  for (int t = 0; t < NTILE; t++){
    int cb = cstart + t*64;
    __syncthreads();   // prior tile's V-frag reads complete
    for (int idx = tid; idx < 64*12; idx += 256){
      int r = idx/12, c4 = idx%12;
      int gc = cb + r; if (gc > NN-1) gc = NN-1;
      *(uint4*)&Vshi[r*SP2 + c4*8] = *(const uint4*)&Vh[(size_t)gc*KP + c4*8];
      *(uint4*)&Vslo[r*SP2 + c4*8] = *(const uint4*)&Vl[(size_t)gc*KP + c4*8];
    }
    __syncthreads();

    f32x4 acc[4];
    #pragma unroll
    for (int ch = 0; ch < 4; ch++) acc[ch] = (f32x4){0.f,0.f,0.f,0.f};
    #pragma unroll
    for (int ks = 0; ks < 3; ks++){
      #pragma unroll
      for (int ch = 0; ch < 4; ch++){
        f16x8 vh = ldfrag(&Vshi[(ch*16 + ln)*SP2 + ks*32 + q*8]);
        f16x8 vl = ldfrag(&Vslo[(ch*16 + ln)*SP2 + ks*32 + q*8]);
        acc[ch] = __builtin_amdgcn_mfma_f32_16x16x32_f16(vh, Uhf[ks], acc[ch], 0, 0, 0);
        acc[ch] = __builtin_amdgcn_mfma_f32_16x16x32_f16(vh, Ulf[ks], acc[ch], 0, 0, 0);
        acc[ch] = __builtin_amdgcn_mfma_f32_16x16x32_f16(vl, Uhf[ks], acc[ch], 0, 0, 0);
      }
    }

    // ---- insert with hierarchical max-prune: lane's 16 scores all belong to row lrow ----
    u32 Treg = rowthr[lrow];
    #pragma unroll
    for (int ch = 0; ch < 4; ch++){
      float mm = fmaxf(fmaxf(acc[ch][0], acc[ch][1]), fmaxf(acc[ch][2], acc[ch][3]));
      if (mm > tv[9] && fkey(mm) > Treg){
        #pragma unroll
        for (int rg = 0; rg < 4; rg++){
          int j = cb + ch*16 + q*4 + rg;
          float v = acc[ch][rg];
          u32 uk = fkey(v);
          if (j < cend && uk > Treg && v > tv[9]){
            bool b[9];
            #pragma unroll
            for (int k = 0; k < 9; k++) b[k] = v > tv[k];
            #pragma unroll
            for (int k = 9; k >= 1; k--){
              bool bh = b[k-1];
              bool bk = (k == 9) ? true : b[k];
              tv[k] = bh ? tv[k-1] : (bk ? v : tv[k]);
              ti[k] = bh ? ti[k-1] : (bk ? j : ti[k]);
            }
            if (b[0]){ tv[0] = v; ti[0] = j; }
            u32 k9 = fkey(tv[9]);
            if (k9 > Treg) Treg = k9;
            atomicMax(&rowthr[lrow], k9);
          }
        }
      }
    }
  }

  // ---- per-block merge of the 4 quad lists per row (overlay on Us) ----
  __syncthreads();
  float* candv = (float*)Us;                   // 64*41 floats
  int*   candi = (int*)((u32*)Us + 64*41);     // 64*41 ints (20992 B <= 26624 B)
  #pragma unroll
  for (int s = 0; s < 10; s++){
    candv[lrow*41 + q*10 + s] = tv[s];
    candi[lrow*41 + q*10 + s] = ti[s];
  }
  __syncthreads();
  if (tid < 64 && r0 + tid < NN){
    int row = tid;
    u32 P = 0;  // 4 x 8-bit pointers
    for (int s = 0; s < 10; s++){
      float bv = NINF; int bi = NN; int by = 0;
      #pragma unroll
      for (int g = 0; g < 4; g++){
        u32 pg = (P >> (8*g)) & 255u;
        u32 pc = pg < 9u ? pg : 9u;
        float v = candv[row*41 + g*10 + pc];
        int  jj = candi[row*41 + g*10 + pc];
        if (pg >= 10u){ v = NINF; jj = NN; }
        if (v > bv || (v == bv && jj < bi)){ bv = v; bi = jj; by = g; }
      }
      P += (1u << (8*by));
      size_t o = ((size_t)y*RCAP + r0 + row)*10 + s;
      ptv[o] = bv; ptc[o] = bi;
    }
  }
}

// ---------------- merge 8 strip partials -> final topk + softplus + dis ----------------
__global__ void k_mergetopk(const float* __restrict__ ptv, const int* __restrict__ ptc,
                            int* __restrict__ topcols, float* __restrict__ topvals,
                            float* __restrict__ dis){
  int r = blockIdx.x*blockDim.x + threadIdx.x;
  if (r >= NN) return;
  const float NINF = -__builtin_inff();
  unsigned long long P = 0;  // 8 x 8-bit pointers
  float d = 1.0f;
  for (int s = 0; s < 10; s++){
    float bv = NINF; int bi = NN; int by = 0;
    #pragma unroll
    for (int g = 0; g < 8; g++){
      u32 pg = (u32)((P >> (8*g)) & 255u);
      u32 pc = pg < 9u ? pg : 9u;
      size_t o = ((size_t)g*RCAP + r)*10 + pc;
      float v = ptv[o]; int jj = ptc[o];
      if (pg >= 10u){ v = NINF; jj = NN; }
      if (v > bv || (v == bv && jj < bi)){ bv = v; bi = jj; by = g; }
    }
    P += (1ull << (8*by));
    float sp = (bv > 20.f) ? bv : log1pf(expf(bv));
    float a = sp - 0.5f; if (a < 0.f) a = 0.f;
    topvals[r*KTOP + s] = a; topcols[r*KTOP + s] = bi;
    d += a;
  }
  dis[r] = rsqrtf(d);
}

// ---------------- CSR (transpose graph) build ----------------
__global__ void k_count(const int* __restrict__ topcols, int* __restrict__ counts){
  int id = blockIdx.x*blockDim.x + threadIdx.x;
  if (id >= NEDGE) return;
  int n = id / (KTOP+1), e = id % (KTOP+1);
  int m = (e < KTOP) ? topcols[n*KTOP+e] : n;
  if ((unsigned)m >= NN) m = n;   // sentinel safety
  atomicAdd(&counts[m], 1);
}

__global__ __launch_bounds__(1024) void k_scan(const int* __restrict__ counts,
                                               int* __restrict__ rowptr, int* __restrict__ cursor){
  __shared__ int part[1024];
  int t = threadIdx.x;
  int local[6];
  int s = 0, base = t*6;
  for (int q = 0; q < 6; q++){
    int i = base + q; int c = (i < NN) ? counts[i] : 0;
    local[q] = s; s += c;
  }
  part[t] = s; __syncthreads();
  for (int off = 1; off < 1024; off <<= 1){
    int v = (t >= off) ? part[t-off] : 0;
    __syncthreads();
    part[t] += v;
    __syncthreads();
  }
  int excl = (t > 0) ? part[t-1] : 0;
  for (int q = 0; q < 6; q++){
    int i = base + q;
    if (i < NN){ int p = excl + local[q]; rowptr[i] = p; cursor[i] = p; }
  }
  if (t == 1023) rowptr[NN] = part[1023];
}

__global__ void k_fill(const int* __restrict__ topcols, const float* __restrict__ topvals,
                       const float* __restrict__ dis, int* __restrict__ cursor,
                       int* __restrict__ csr_src, float* __restrict__ csr_w){
  int id = blockIdx.x*blockDim.x + threadIdx.x;
  if (id >= NEDGE) return;
  int n = id / (KTOP+1), e = id % (KTOP+1);
  int m; float v;
  if (e < KTOP){ m = topcols[n*KTOP+e]; v = topvals[n*KTOP+e]; }
  else { m = n; v = 1.0f; }
  if ((unsigned)m >= NN){ m = n; v = 0.0f; }   // sentinel safety
  float w = v * dis[n] * dis[m];
  int pos = atomicAdd(&cursor[m], 1);
  csr_src[pos] = n; csr_w[pos] = w;
}

// ---------------- scatter (last occurrence wins, numpy semantics) ----------------
__global__ void k_winner(const int* __restrict__ idx, int* __restrict__ winner){
  int s = blockIdx.x*blockDim.x + threadIdx.x;
  if (s >= NSUB) return;
  atomicMax(&winner[idx[s]], s);
}

__global__ void k_h0(const float* __restrict__ subset, const float* __restrict__ uinit,
                     const int* __restrict__ winner, u16* __restrict__ h){
  int id = blockIdx.x*blockDim.x + threadIdx.x;
  if (id >= ROWS*(DD/2)) return;
  int c2 = id % (DD/2); int bn = id / (DD/2); int n = bn % NN; int b = bn / NN;
  int w = winner[n];
  float2 v;
  if (w >= 0) v = *(const float2*)&subset[((size_t)b*NSUB + w)*DD + c2*2];
  else        v = *(const float2*)&uinit[c2*2];
  ((u32*)h)[id] = (u32)f2b(v.x) | ((u32)f2b(v.y) << 16);
}

// ---------------- weight transpose/convert: wbf[mat][n][k] = W[k][n] ----------------
__global__ void k_wprep(const float* __restrict__ mlp_w, const float* __restrict__ gate_w,
                        const float* __restrict__ diff_w, u16* __restrict__ wbf){
  int id = blockIdx.x*blockDim.x + threadIdx.x;
  if (id >= NLAY*5*WMAT) return;
  int mat = id / WMAT, rem = id % WMAT;
  int n = rem / DD, k = rem % DD;
  int layer = mat / 5, which = mat % 5;
  float v;
  if (which == 0)      v = mlp_w [((size_t)layer*DD   + k      )*DD + n];
  else if (which == 1) v = gate_w[((size_t)layer*2*DD + k      )*DD + n];
  else if (which == 2) v = gate_w[((size_t)layer*2*DD + DD + k )*DD + n];
  else if (which == 3) v = diff_w[((size_t)layer*2*DD + k      )*DD + n];
  else                 v = diff_w[((size_t)layer*2*DD + DD + k )*DD + n];
  wbf[id] = f2b(v);
}

// ---------------- SpMM: agg[b,m,:] = sum_in-edges w * h[b,src,:] ----------------
// thread = (8-channel group c8 0..23, batch b 0..7); one dwordx4 gather per edge.
__global__ __launch_bounds__(192) void k_spmm(const u16* __restrict__ h, const int* __restrict__ rowptr,
                       const int* __restrict__ csr_src, const float* __restrict__ csr_w,
                       u16* __restrict__ agg){
  __shared__ int s_src[128]; __shared__ float s_w[128];
  int m = blockIdx.x;
  int c8 = threadIdx.x % 24;
  int b  = threadIdx.x / 24;
  int beg = rowptr[m], end = rowptr[m+1];
  float acc[8];
  #pragma unroll
  for (int i = 0; i < 8; i++) acc[i] = 0.f;
  for (int base = beg; base < end; base += 128){
    int cnt = end - base; if (cnt > 128) cnt = 128;
    __syncthreads();
    for (int e = threadIdx.x; e < cnt; e += 192){ s_src[e] = csr_src[base+e]; s_w[e] = csr_w[base+e]; }
    __syncthreads();
    for (int e = 0; e < cnt; e++){
      int src = s_src[e]; float w = s_w[e];
      uint4 pk = *(const uint4*)&h[((size_t)b*NN + src)*DD + c8*8];
      u32 ws[4] = {pk.x, pk.y, pk.z, pk.w};
      #pragma unroll
      for (int t2 = 0; t2 < 4; t2++){
        u32 u = ws[t2];
        acc[t2*2]   += w * __uint_as_float(u << 16);
        acc[t2*2+1] += w * __uint_as_float(u & 0xffff0000u);
      }
    }
  }
  uint4 o;
  o.x = (u32)f2b(acc[0]) | ((u32)f2b(acc[1]) << 16);
  o.y = (u32)f2b(acc[2]) | ((u32)f2b(acc[3]) << 16);
  o.z = (u32)f2b(acc[4]) | ((u32)f2b(acc[5]) << 16);
  o.w = (u32)f2b(acc[6]) | ((u32)f2b(acc[7]) << 16);
  *(uint4*)&agg[((size_t)b*NN + m)*DD + c8*8] = o;
}

// ---------------- fused layer: hn / gate / highway / diffusion (bf16 MFMA) ----------------
// Wave w owns col-tiles {3w,3w+1,3w+2}; B fragments register-resident per stage.
#define LP 200  // LDS row pitch in bf16 elems (192 + 8 pad)
__global__ __launch_bounds__(256, 2) void k_layer(u16* __restrict__ h, const u16* __restrict__ agg,
                        const u16* __restrict__ wl, const float* __restrict__ mb,
                        const float* __restrict__ gb, const float* __restrict__ db){
  __shared__ u16 Ah[64*LP];
  __shared__ u16 Ax[64*LP];
  const int tid = threadIdx.x, lane = tid & 63, wave = tid >> 6;
  const int q = lane >> 4, ln = lane & 15;
  const int row0 = blockIdx.x*64;

  for (int i = tid; i < 64*24; i += 256){
    int r = i/24, c0 = i%24;
    ((uint4*)&Ah[r*LP])[c0] = ((const uint4*)h  )[(size_t)(row0+r)*24 + c0];
    ((uint4*)&Ax[r*LP])[c0] = ((const uint4*)agg)[(size_t)(row0+r)*24 + c0];
  }
  __syncthreads();

  const u16 *Wm = wl, *G1 = wl + WMAT, *G2 = wl + 2*WMAT, *D1 = wl + 3*WMAT, *D2 = wl + 4*WMAT;

  f32x4 acc[4][3];
  bf16x8 Bf[6][3];

  auto loadB = [&](const u16* wp){
    #pragma unroll
    for (int kk = 0; kk < 6; kk++)
      #pragma unroll
      for (int ntl = 0; ntl < 3; ntl++){
        int nt = wave*3 + ntl;
        Bf[kk][ntl] = *(const bf16x8*)&wp[(size_t)(nt*16 + ln)*DD + kk*32 + q*8];
      }
  };
  auto gemm = [&](const u16* Al){
    #pragma unroll
    for (int kk = 0; kk < 6; kk++){
      bf16x8 a[4];
      #pragma unroll
      for (int rt = 0; rt < 4; rt++)
        a[rt] = *(const bf16x8*)&Al[(rt*16 + ln)*LP + kk*32 + q*8];
      #pragma unroll
      for (int rt = 0; rt < 4; rt++)
        #pragma unroll
        for (int ntl = 0; ntl < 3; ntl++)
          acc[rt][ntl] = __builtin_amdgcn_mfma_f32_16x16x32_bf16(a[rt], Bf[kk][ntl], acc[rt][ntl], 0, 0, 0);
    }
  };
  auto zacc = [&](){
    #pragma unroll
    for (int rt = 0; rt < 4; rt++)
      #pragma unroll
      for (int ntl = 0; ntl < 3; ntl++)
        acc[rt][ntl] = (f32x4){0.f, 0.f, 0.f, 0.f};
  };

  // ---- stage 1: hn = agg @ Wm + mb  -> Ax
  zacc(); loadB(Wm); gemm(Ax);
  __syncthreads();
  #pragma unroll
  for (int ntl = 0; ntl < 3; ntl++){
    int col = (wave*3 + ntl)*16 + ln; float bias = mb[col];
    #pragma unroll
    for (int rt = 0; rt < 4; rt++)
      #pragma unroll
      for (int r = 0; r < 4; r++)
        Ax[(rt*16 + q*4 + r)*LP + col] = f2b(acc[rt][ntl][r] + bias);
  }
  __syncthreads();

  // ---- stage 2: g = sigmoid(h@G1 + hn@G2 + gb); lo = g*hn + (1-g)*h -> Ax
  zacc(); loadB(G1); gemm(Ah); loadB(G2); gemm(Ax);
  __syncthreads();
  #pragma unroll
  for (int ntl = 0; ntl < 3; ntl++){
    int col = (wave*3 + ntl)*16 + ln; float bias = gb[col];
    #pragma unroll
    for (int rt = 0; rt < 4; rt++)
      #pragma unroll
      for (int r = 0; r < 4; r++){
        int off = (rt*16 + q*4 + r)*LP + col;
        float g = 1.f/(1.f + expf(-(acc[rt][ntl][r] + bias)));
        float hv = b2f(Ah[off]), hnv = b2f(Ax[off]);
        Ax[off] = f2b(g*hnv + (1.f - g)*hv);
      }
  }
  __syncthreads();

  // ---- stage 3: dg = sigmoid(h@D1 + lo@D2 + db); h' = dg*lo + (1-dg)*h -> global
  zacc(); loadB(D1); gemm(Ah); loadB(D2); gemm(Ax);
  #pragma unroll
  for (int ntl = 0; ntl < 3; ntl++){
    int col = (wave*3 + ntl)*16 + ln; float bias = db[col];
    #pragma unroll
    for (int rt = 0; rt < 4; rt++)
      #pragma unroll
      for (int r = 0; r < 4; r++){
        int row = rt*16 + q*4 + r; int off = row*LP + col;
        float dg = 1.f/(1.f + expf(-(acc[rt][ntl][r] + bias)));
        float lov = b2f(Ax[off]), hv = b2f(Ah[off]);
        h[(size_t)(row0 + row)*DD + col] = f2b(dg*lov + (1.f - dg)*hv);
      }
  }
}

// ---------------- final confidence fusion (fp32 h0 path kept exact) ----------------
__global__ void k_final(const u16* __restrict__ h, const float* __restrict__ subset,
                        const int* __restrict__ winner, const float* __restrict__ ca_p,
                        float* __restrict__ out){
  int id = blockIdx.x*blockDim.x + threadIdx.x;
  if (id >= ROWS*(DD/2)) return;
  int c2 = id % (DD/2); int bn = id / (DD/2); int n = bn % NN; int b = bn / NN;
  float ca = ca_p[0];
  int w = winner[n];
  u32 hp = ((const u32*)h)[id];
  float hlo = __uint_as_float(hp << 16);
  float hhi = __uint_as_float(hp & 0xffff0000u);
  float2 o;
  if (w >= 0){
    float2 h0 = *(const float2*)&subset[((size_t)b*NSUB + w)*DD + c2*2];
    o.x = (1.0f - ca)*h0.x + ca*hlo;
    o.y = (1.0f - ca)*h0.y + ca*hhi;
  } else {
    o.x = hlo; o.y = hhi;
  }
  *(float2*)&out[(size_t)bn*DD + c2*2] = o;
}

extern "C" void kernel_launch(void* const* d_in, const int* in_sizes, int n_in,
                              void* d_out, int out_size, void* d_ws, size_t ws_size,
                              hipStream_t stream) {
  const float* subset = (const float*)d_in[0];
  const int*   idxs   = (const int*)  d_in[1];
  const float* emb1   = (const float*)d_in[2];
  const float* emb2   = (const float*)d_in[3];
  const float* l1w    = (const float*)d_in[4];
  const float* l1b    = (const float*)d_in[5];
  const float* l2w    = (const float*)d_in[6];
  const float* l2b    = (const float*)d_in[7];
  const float* uinit  = (const float*)d_in[8];
  const float* mlp_w  = (const float*)d_in[9];
  const float* mlp_b  = (const float*)d_in[10];
  const float* gate_w = (const float*)d_in[11];
  const float* gate_b = (const float*)d_in[12];
  const float* diff_w = (const float*)d_in[13];
  const float* diff_b = (const float*)d_in[14];
  const float* ca     = (const float*)d_in[15];
  float* out = (float*)d_out;

  char* base = (char*)d_ws; size_t off = 0;
  auto alloc = [&](size_t b)->void*{ void* p = base + off; off += b; off = (off + 255) & ~(size_t)255; return p; };
  u16*   Uht     = (u16*)  alloc((size_t)NN*KP*2);
  u16*   Ult     = (u16*)  alloc((size_t)NN*KP*2);
  u16*   Vht     = (u16*)  alloc((size_t)NN*KP*2);
  u16*   Vlt     = (u16*)  alloc((size_t)NN*KP*2);
  u16*   h       = (u16*)  alloc((size_t)ROWS*DD*2);
  u16*   agg     = (u16*)  alloc((size_t)ROWS*DD*2);
  u16*   wbf     = (u16*)  alloc((size_t)NLAY*5*WMAT*2);
  int*   topcols = (int*)  alloc((size_t)NN*KTOP*4);
  float* topvals = (float*)alloc((size_t)NN*KTOP*4);
  float* dis     = (float*)alloc((size_t)NN*4);
  int*   winner  = (int*)  alloc((size_t)NN*4);
  int*   counts  = (int*)  alloc((size_t)NN*4);
  int*   rowptr  = (int*)  alloc((size_t)(NN+1)*4);
  int*   cursor  = (int*)  alloc((size_t)NN*4);
  int*   csr_src = (int*)  alloc((size_t)NEDGE*4);
  float* csr_w   = (float*)alloc((size_t)NEDGE*4);
  float* ptv     = (float*)alloc((size_t)NSTRIP*RCAP*KTOP*4);
  int*   ptc     = (int*)  alloc((size_t)NSTRIP*RCAP*KTOP*4);

  // 1. graph constructor tables (f16 hi/lo, padded to 96)
  k_prep_uv<<<(NN*GD + 255)/256, 256, 0, stream>>>(emb1, emb2, l1w, l1b, l2w, l2b,
                                                   Uht, Ult, Vht, Vlt);

  // 2. fused score + top-k, then strip merge
  dim3 gs(94, NSTRIP);
  k_scoretopk<<<gs, 256, 0, stream>>>(Uht, Ult, Vht, Vlt, ptv, ptc);
  k_mergetopk<<<(NN + 255)/256, 256, 0, stream>>>(ptv, ptc, topcols, topvals, dis);

  // 3. CSR of transpose graph
  hipMemsetAsync(counts, 0, (size_t)NN*4, stream);
  k_count<<<(NEDGE + 255)/256, 256, 0, stream>>>(topcols, counts);
  k_scan<<<1, 1024, 0, stream>>>(counts, rowptr, cursor);
  k_fill<<<(NEDGE + 255)/256, 256, 0, stream>>>(topcols, topvals, dis, cursor, csr_src, csr_w);

  // 4. scatter init
  hipMemsetAsync(winner, 0xFF, (size_t)NN*4, stream);
  k_winner<<<(NSUB + 255)/256, 256, 0, stream>>>(idxs, winner);
  k_h0<<<(ROWS*(DD/2) + 255)/256, 256, 0, stream>>>(subset, uinit, winner, h);

  // 5. weights -> bf16 transposed
  k_wprep<<<(NLAY*5*WMAT + 255)/256, 256, 0, stream>>>(mlp_w, gate_w, diff_w, wbf);

  // 6. layers
  for (int l = 0; l < NLAY; l++){
    k_spmm<<<NN, 192, 0, stream>>>(h, rowptr, csr_src, csr_w, agg);
    k_layer<<<ROWS/64, 256, 0, stream>>>(h, agg, wbf + (size_t)l*5*WMAT,
                                         mlp_b + l*DD, gate_b + l*DD, diff_b + l*DD);
  }

  // 7. confidence fusion
  k_final<<<(ROWS*(DD/2) + 255)/256, 256, 0, stream>>>(h, subset, winner, ca, out);
}